// Round 10
// baseline (2162.434 us; speedup 1.0000x reference)
//
#include <hip/hip_runtime.h>
#include <hip/hip_fp16.h>

// Problem constants (match reference)
#define N_NODES 100000
#define N_EDGES 1600000
#define CCH     128
#define BG      512
#define NHID    512
#define NOUT    256
#define BN_EPS  1e-5f
// padded CSR capacity: sum ceil(d/4)*4 <= E + 3N, +128 tail pad
#define CSR_CAP (N_EDGES + 4 * N_NODES + 128)

typedef __attribute__((ext_vector_type(8))) short s16x8;
typedef __attribute__((ext_vector_type(4))) float f32x4;

static __device__ __forceinline__ float leaky(float x) { return x > 0.f ? x : 0.2f * x; }
static __device__ __forceinline__ uint32_t bfr16(float x) {
  uint32_t u = __float_as_uint(x);
  u += 0x7fffu + ((u >> 16) & 1u);
  return u >> 16;
}
static __device__ __forceinline__ uint32_t pack2(float a, float b) {
  return bfr16(a) | (bfr16(b) << 16);
}
static __device__ __forceinline__ float blo(uint32_t u) { return __uint_as_float(u << 16); }
static __device__ __forceinline__ float bhi(uint32_t u) { return __uint_as_float(u & 0xffff0000u); }
static __device__ __forceinline__ uint32_t packh2(float a, float b) {
  __half2 h;
  h.x = __float2half(a);
  h.y = __float2half(b);
  return *reinterpret_cast<uint32_t*>(&h);
}
static __device__ __forceinline__ float hlo(uint32_t u) {
  __half2 h = *reinterpret_cast<__half2*>(&u);
  return __half2float(h.x);
}
static __device__ __forceinline__ float hhi(uint32_t u) {
  __half2 h = *reinterpret_cast<__half2*>(&u);
  return __half2float(h.y);
}

// ---------------- graph prep ----------------
__global__ void hist_kernel(const int* __restrict__ dst, int* __restrict__ indeg) {
  int e = blockIdx.x * 256 + threadIdx.x;
  if (e < N_EDGES) atomicAdd(&indeg[dst[e]], 1);
}

// scan over PADDED degrees (ceil(d/4)*4); 1024 elems/block
__global__ __launch_bounds__(256) void scan_chunks(const int* __restrict__ indeg,
                                                   int* __restrict__ rowstart,
                                                   int* __restrict__ chunksum) {
  int tid = threadIdx.x;
  int base = blockIdx.x * 1024 + tid * 4;
  int4 v;
  if (base + 3 < N_NODES) {
    v = *(const int4*)(indeg + base);
  } else {
    v.x = (base + 0 < N_NODES) ? indeg[base + 0] : 0;
    v.y = (base + 1 < N_NODES) ? indeg[base + 1] : 0;
    v.z = (base + 2 < N_NODES) ? indeg[base + 2] : 0;
    v.w = (base + 3 < N_NODES) ? indeg[base + 3] : 0;
  }
  int px = (v.x + 3) & ~3, py = (v.y + 3) & ~3, pz = (v.z + 3) & ~3, pw = (v.w + 3) & ~3;
  int s = px + py + pz + pw;
  __shared__ int ss[256];
  ss[tid] = s;
  __syncthreads();
  for (int off = 1; off < 256; off <<= 1) {
    int t = (tid >= off) ? ss[tid - off] : 0;
    __syncthreads();
    ss[tid] += t;
    __syncthreads();
  }
  int excl = ss[tid] - s;
  if (base + 0 < N_NODES) rowstart[base + 0] = excl;
  if (base + 1 < N_NODES) rowstart[base + 1] = excl + px;
  if (base + 2 < N_NODES) rowstart[base + 2] = excl + px + py;
  if (base + 3 < N_NODES) rowstart[base + 3] = excl + px + py + pz;
  if (tid == 255) chunksum[blockIdx.x] = ss[255];
}

// merged: chunk-prefix finalize + dinv + degree-bucket histogram
__global__ __launch_bounds__(256) void scan_finish(const int* __restrict__ chunksum,
                                                   int* __restrict__ rowstart,
                                                   const int* __restrict__ indeg,
                                                   float* __restrict__ dinv,
                                                   int* __restrict__ gcnt) {
  __shared__ int ss[128];
  __shared__ int ex[128];
  int tid = threadIdx.x;
  int v0 = 0;
  if (tid < 128) { v0 = (tid < 98) ? chunksum[tid] : 0; ss[tid] = v0; }
  __syncthreads();
  for (int off = 1; off < 128; off <<= 1) {
    int t = 0;
    if (tid < 128 && tid >= off) t = ss[tid - off];
    __syncthreads();
    if (tid < 128) ss[tid] += t;
    __syncthreads();
  }
  if (tid < 128) ex[tid] = ss[tid] - v0;   // exclusive chunk prefix
  __syncthreads();
  int i = blockIdx.x * 256 + tid;
  if (i < N_NODES) {
    rowstart[i] += ex[i >> 10];
    int d = indeg[i];
    dinv[i] = rsqrtf((float)(d + 1));
    int g = (d + 3) >> 2;
    if (g > 63) g = 63;
    atomicAdd(&gcnt[g], 1);
  } else if (i == N_NODES) {
    rowstart[N_NODES] = ss[97];
  }
}

// degree-sorted permutation (descending bucket order -> similar-degree pairs)
__global__ __launch_bounds__(256) void scatter_perm(const int* __restrict__ indeg,
                                                    const int* __restrict__ gcnt,
                                                    int* __restrict__ gcur,
                                                    int* __restrict__ perm) {
  __shared__ int start[64];
  int tid = threadIdx.x;
  if (tid < 64) {
    int s = 0;
    for (int j = tid + 1; j < 64; ++j) s += gcnt[j];
    start[tid] = s;
  }
  __syncthreads();
  int n = blockIdx.x * 256 + tid;
  if (n < N_NODES) {
    int d = indeg[n];
    int g = (d + 3) >> 2;
    if (g > 63) g = 63;
    int pos = start[g] + atomicAdd(&gcur[g], 1);
    perm[pos] = n;
  }
}

__global__ void scatter_edges(const int* __restrict__ src, const int* __restrict__ dst,
                              const int* __restrict__ rowstart, int* __restrict__ cursor,
                              const float* __restrict__ dinv, int2* __restrict__ csr_sw) {
  int e = blockIdx.x * 256 + threadIdx.x;
  if (e < N_EDGES) {
    int d = dst[e];
    int s = src[e];
    int p = rowstart[d] + atomicAdd(&cursor[d], 1);
    float w = dinv[s] * dinv[d];   // > 0 always (pad sentinel relies on this)
    csr_sw[p] = make_int2(s, __float_as_int(w));
  }
}

// ---------------- prep: cast x + pack conv weights + pack MLP weights (one dispatch) ----
__global__ void prep_kernel(const float2* __restrict__ x2, uint32_t* __restrict__ xb,
                            const float* __restrict__ W1, const float* __restrict__ W2,
                            const float* __restrict__ W3, const float* __restrict__ W4,
                            unsigned short* __restrict__ Wp1, unsigned short* __restrict__ Wp2,
                            unsigned short* __restrict__ Wp3, unsigned short* __restrict__ Wp4,
                            const float* __restrict__ Wh1, const float* __restrict__ Wm0,
                            const float* __restrict__ Wm1, const float* __restrict__ Wo,
                            unsigned short* __restrict__ P1, unsigned short* __restrict__ P2,
                            unsigned short* __restrict__ P3, unsigned short* __restrict__ P4) {
  int b = blockIdx.x;
  if (b < 25000) {
    size_t idx = (size_t)b * 256 + threadIdx.x;
    float2 v = x2[idx];
    xb[idx] = pack2(v.x, v.y);
    return;
  }
  if (b < 25032) {
    int pb = b - 25000;
    int wsel = pb >> 3;
    int t = (pb & 7) * 256 + threadIdx.x;
    const float* W = (wsel == 0) ? W1 : (wsel == 1) ? W2 : (wsel == 2) ? W3 : W4;
    unsigned short* Wp = (wsel == 0) ? Wp1 : (wsel == 1) ? Wp2 : (wsel == 2) ? Wp3 : Wp4;
    int lane = t & 63;
    int ks = (t >> 6) & 3;
    int nt = t >> 8;
    int c = nt * 16 + (lane & 15);
    int kb = ks * 32 + (lane >> 4) * 8;
#pragma unroll
    for (int i = 0; i < 8; ++i)
      Wp[(size_t)t * 8 + i] = (unsigned short)bfr16(W[(size_t)(kb + i) * 128 + c]);
    return;
  }
  // MLP weight packing
  int t = (b - 25032) * 256 + threadIdx.x;
  const float* W;
  unsigned short* P;
  int K, N, loc;
  if (t < 8192)        { W = Wh1; P = P1; K = 128; N = 512; loc = t; }
  else if (t < 40960)  { W = Wm0; P = P2; K = 512; N = 512; loc = t - 8192; }
  else if (t < 73728)  { W = Wm1; P = P3; K = 512; N = 512; loc = t - 40960; }
  else if (t < 90112)  { W = Wo;  P = P4; K = 512; N = 256; loc = t - 73728; }
  else return;
  int ksn = K >> 5;
  int lane = loc & 63;
  int ks = (loc >> 6) & (ksn - 1);
  int nt = loc / (64 * ksn);
  int c = nt * 16 + (lane & 15);
  int kb = ks * 32 + (lane >> 4) * 8;
#pragma unroll
  for (int i = 0; i < 8; ++i)
    P[(size_t)loc * 8 + i] = (unsigned short)bfr16(W[(size_t)(kb + i) * N + c]);
}

// ---------------- MFMA conv GEMM, optionally fusing BN+ReLU+residual on the A side ------
template <int FUSE>
__global__ __launch_bounds__(256) void gemm_mfma(uint32_t* __restrict__ xbm,
                                                 const uint32_t* __restrict__ aggb,   // fp16 pairs
                                                 const float* __restrict__ stats,
                                                 const float* __restrict__ gamma,
                                                 const float* __restrict__ beta,
                                                 const unsigned short* __restrict__ Wp,
                                                 uint32_t* __restrict__ Hb,
                                                 int M) {
  __shared__ float scs[128], bcs[128];
  if (FUSE) {
    int t = threadIdx.x;
    if (t < 128) {
      const float n_inv = 1.f / (float)N_NODES;
      float m = stats[t] * n_inv;
      float v = stats[128 + t] * n_inv - m * m;
      float s = gamma[t] * rsqrtf(v + BN_EPS);
      scs[t] = s;
      bcs[t] = beta[t] - m * s;
    }
    __syncthreads();
  }
  int wave = threadIdx.x >> 6, lane = threadIdx.x & 63;
  int row0 = blockIdx.x * 128 + wave * 32;
  int r = lane & 15, g = lane >> 4;

  f32x4 acc[2][8];
#pragma unroll
  for (int mt = 0; mt < 2; ++mt)
#pragma unroll
    for (int nt = 0; nt < 8; ++nt) acc[mt][nt] = (f32x4){0.f, 0.f, 0.f, 0.f};

  s16x8 a[2][4];
#pragma unroll
  for (int mt = 0; mt < 2; ++mt) {
    int row = row0 + mt * 16 + r;
    bool v = row < M;
    if (FUSE) {
#pragma unroll
      for (int ks = 0; ks < 4; ++ks) {
        int ch = ks * 32 + g * 8;
        s16x8 af = {0, 0, 0, 0, 0, 0, 0, 0};
        if (v) {
          uint4 av4 = *(const uint4*)(aggb + (size_t)row * 64 + (ch >> 1));
          uint4 xo = *(const uint4*)(xbm + (size_t)row * 64 + (ch >> 1));
          float aa[8] = {hlo(av4.x), hhi(av4.x), hlo(av4.y), hhi(av4.y),
                         hlo(av4.z), hhi(av4.z), hlo(av4.w), hhi(av4.w)};
          float xold[8] = {blo(xo.x), bhi(xo.x), blo(xo.y), bhi(xo.y),
                           blo(xo.z), bhi(xo.z), blo(xo.w), bhi(xo.w)};
          uint32_t pk[4];
#pragma unroll
          for (int jj = 0; jj < 4; ++jj) {
            float r0v = fmaxf(fmaf(aa[2 * jj],     scs[ch + 2 * jj],     bcs[ch + 2 * jj]),     0.f) + xold[2 * jj];
            float r1v = fmaxf(fmaf(aa[2 * jj + 1], scs[ch + 2 * jj + 1], bcs[ch + 2 * jj + 1]), 0.f) + xold[2 * jj + 1];
            pk[jj] = pack2(r0v, r1v);
          }
          uint4 st = make_uint4(pk[0], pk[1], pk[2], pk[3]);
          *(uint4*)(xbm + (size_t)row * 64 + (ch >> 1)) = st;
          af = *(s16x8*)&st;
        }
        a[mt][ks] = af;
      }
    } else {
      const unsigned short* ap = (const unsigned short*)xbm + (size_t)row * 128 + g * 8;
#pragma unroll
      for (int ks = 0; ks < 4; ++ks) {
        s16x8 af = {0, 0, 0, 0, 0, 0, 0, 0};
        if (v) af = *(const s16x8*)(ap + ks * 32);
        a[mt][ks] = af;
      }
    }
  }
#pragma unroll
  for (int ks = 0; ks < 4; ++ks) {
#pragma unroll
    for (int nt = 0; nt < 8; ++nt) {
      s16x8 bfr = *(const s16x8*)(Wp + ((size_t)(nt * 4 + ks) * 64 + lane) * 8);
      acc[0][nt] = __builtin_amdgcn_mfma_f32_16x16x32_bf16(a[0][ks], bfr, acc[0][nt], 0, 0, 0);
      acc[1][nt] = __builtin_amdgcn_mfma_f32_16x16x32_bf16(a[1][ks], bfr, acc[1][nt], 0, 0, 0);
    }
  }
#pragma unroll
  for (int mt = 0; mt < 2; ++mt) {
#pragma unroll
    for (int nt = 0; nt < 8; ++nt) {
#pragma unroll
      for (int reg = 0; reg < 4; ++reg) {
        float v0 = acc[mt][nt][reg];
        float v1 = __shfl_xor(v0, 1);
        int row = row0 + mt * 16 + (lane >> 4) * 4 + reg;
        int col = nt * 16 + (lane & 15);
        if (!(lane & 1) && row < M)
          Hb[(size_t)row * 64 + (col >> 1)] = pack2(v0, v1);
      }
    }
  }
}

// ---------------- MLP MFMA GEMM ----------------
template <int RELU, int OUTF32>
__global__ __launch_bounds__(256) void gemm_mlp(const uint32_t* __restrict__ Ab,
                                                const unsigned short* __restrict__ Wp,
                                                const float* __restrict__ bias,
                                                void* __restrict__ outp,
                                                int M, int K, int N) {
  int wave = threadIdx.x >> 6, lane = threadIdx.x & 63;
  int row0 = blockIdx.x * 128 + wave * 32;
  int colb = blockIdx.y;
  const unsigned short* A16 = (const unsigned short*)Ab;
  int KS = K >> 5;
  int r = lane & 15, g = lane >> 4;
  f32x4 acc[2][8];
#pragma unroll
  for (int mt = 0; mt < 2; ++mt)
#pragma unroll
    for (int nt = 0; nt < 8; ++nt) acc[mt][nt] = (f32x4){0.f, 0.f, 0.f, 0.f};

  for (int ks = 0; ks < KS; ++ks) {
    s16x8 a[2];
#pragma unroll
    for (int mt = 0; mt < 2; ++mt) {
      int row = row0 + mt * 16 + r;
      s16x8 af = {0, 0, 0, 0, 0, 0, 0, 0};
      if (row < M) af = *(const s16x8*)(A16 + (size_t)row * K + ks * 32 + g * 8);
      a[mt] = af;
    }
#pragma unroll
    for (int ntl = 0; ntl < 8; ++ntl) {
      int ntg = colb * 8 + ntl;
      s16x8 b = *(const s16x8*)(Wp + ((size_t)(ntg * KS + ks) * 64 + lane) * 8);
      acc[0][ntl] = __builtin_amdgcn_mfma_f32_16x16x32_bf16(a[0], b, acc[0][ntl], 0, 0, 0);
      acc[1][ntl] = __builtin_amdgcn_mfma_f32_16x16x32_bf16(a[1], b, acc[1][ntl], 0, 0, 0);
    }
  }
#pragma unroll
  for (int mt = 0; mt < 2; ++mt) {
#pragma unroll
    for (int ntl = 0; ntl < 8; ++ntl) {
#pragma unroll
      for (int reg = 0; reg < 4; ++reg) {
        int row = row0 + mt * 16 + (lane >> 4) * 4 + reg;
        int col = colb * 128 + ntl * 16 + (lane & 15);
        float v0 = acc[mt][ntl][reg] + bias[col];
        if (RELU) v0 = fmaxf(v0, 0.f);
        if (OUTF32) {
          if (row < M) ((float*)outp)[(size_t)row * N + col] = v0;
        } else {
          float v1 = __shfl_xor(v0, 1);
          if (!(lane & 1) && row < M)
            ((uint32_t*)outp)[(size_t)row * (N >> 1) + (col >> 1)] = pack2(v0, v1);
        }
      }
    }
  }
}

// ---------------- unified aggregation: degree-matched pairs, padded rows, depth-2 pipeline --
template <int GAT>
__global__ __launch_bounds__(256) void agg_kernel(const uint2* __restrict__ Hb2,
                                                  const int* __restrict__ rowstart,
                                                  const int2* __restrict__ pack,
                                                  const int* __restrict__ perm,
                                                  const float* __restrict__ dinv,
                                                  const int* __restrict__ indeg,
                                                  const float* __restrict__ es,
                                                  const float* __restrict__ ed,
                                                  uint32_t* __restrict__ aggb,
                                                  float* __restrict__ stats) {
  const float INVALW = GAT ? -1e30f : 0.0f;
  int tid = threadIdx.x;
  int lane = tid & 63;
  int hl = lane & 31;
  int half = lane >> 5;
  int gw = (blockIdx.x * 256 + tid) >> 6;
  int nw = (gridDim.x * 256) >> 6;
  float s0 = 0, s1 = 0, s2 = 0, s3 = 0, q0 = 0, q1 = 0, q2 = 0, q3 = 0;

#define LOADPK(gq, I0, I1, I2, I3, V0, V1, V2, V3)                        \
  do {                                                                    \
    bool ok = (gq) < G;                                                   \
    int ee = e0 + (gq) * 4;                                               \
    int2 pa = pack[ee], pb = pack[ee + 1], pc = pack[ee + 2], pd = pack[ee + 3]; \
    I0 = ok ? pa.x : 0; V0 = ok ? __int_as_float(pa.y) : INVALW;          \
    I1 = ok ? pb.x : 0; V1 = ok ? __int_as_float(pb.y) : INVALW;          \
    I2 = ok ? pc.x : 0; V2 = ok ? __int_as_float(pc.y) : INVALW;          \
    I3 = ok ? pd.x : 0; V3 = ok ? __int_as_float(pd.y) : INVALW;          \
  } while (0)

  for (int pi = gw; pi < N_NODES / 2; pi += nw) {
    int n = perm[2 * pi + half];
    int e0 = rowstart[n], e1p = rowstart[n + 1];
    int G = (e1p - e0) >> 2;
    int Gmax = max(G, __shfl_xor(G, 32));
    float edi = 0.f, selfw, fscale = 1.f;
    if (GAT) {
      int len = indeg[n];
      edi = ed[n];
      float wself = __expf(leaky(es[n] + edi));
      float wsum = (hl == 0) ? wself : 0.f;
      for (int e = e0 + hl; e < e0 + len; e += 32)
        wsum += __expf(leaky(__int_as_float(pack[e].y) + edi));
#pragma unroll
      for (int off = 16; off; off >>= 1) wsum += __shfl_xor(wsum, off);
      fscale = 1.f / (wsum + 1e-16f);
      selfw = wself;
    } else {
      float di = dinv[n];
      selfw = di * di;
    }
    uint2 hs = Hb2[(size_t)n * 32 + hl];
    float c0 = blo(hs.x) * selfw, c1 = bhi(hs.x) * selfw;
    float c2 = blo(hs.y) * selfw, c3 = bhi(hs.y) * selfw;

    if (Gmax > 0) {
      int j0, j1, j2, j3;
      float wC0, wC1, wC2, wC3;
      float wB0, wB1, wB2, wB3;
      float wA0, wA1, wA2, wA3;
      uint2 R00, R01, R02, R03;
      uint2 R10, R11, R12, R13;
      LOADPK(0, j0, j1, j2, j3, wC0, wC1, wC2, wC3);
      R00 = Hb2[(size_t)(unsigned)j0 * 32 + hl];
      R01 = Hb2[(size_t)(unsigned)j1 * 32 + hl];
      R02 = Hb2[(size_t)(unsigned)j2 * 32 + hl];
      R03 = Hb2[(size_t)(unsigned)j3 * 32 + hl];
      LOADPK(1, j0, j1, j2, j3, wB0, wB1, wB2, wB3);
      R10 = Hb2[(size_t)(unsigned)j0 * 32 + hl];
      R11 = Hb2[(size_t)(unsigned)j1 * 32 + hl];
      R12 = Hb2[(size_t)(unsigned)j2 * 32 + hl];
      R13 = Hb2[(size_t)(unsigned)j3 * 32 + hl];
      LOADPK(2, j0, j1, j2, j3, wA0, wA1, wA2, wA3);
      for (int g = 0; g < Gmax; ++g) {
        uint2 R20, R21, R22, R23;
        if (g + 2 < Gmax) {
          R20 = Hb2[(size_t)(unsigned)j0 * 32 + hl];
          R21 = Hb2[(size_t)(unsigned)j1 * 32 + hl];
          R22 = Hb2[(size_t)(unsigned)j2 * 32 + hl];
          R23 = Hb2[(size_t)(unsigned)j3 * 32 + hl];
        }
        int k0, k1, k2, k3;
        float wN0, wN1, wN2, wN3;
        if (g + 3 < Gmax) {
          LOADPK(g + 3, k0, k1, k2, k3, wN0, wN1, wN2, wN3);
        } else {
          k0 = k1 = k2 = k3 = 0;
          wN0 = wN1 = wN2 = wN3 = INVALW;
        }
        float f0, f1, f2, f3;
        if (GAT) {
          f0 = __expf(leaky(wC0 + edi)); f1 = __expf(leaky(wC1 + edi));
          f2 = __expf(leaky(wC2 + edi)); f3 = __expf(leaky(wC3 + edi));
        } else {
          f0 = wC0; f1 = wC1; f2 = wC2; f3 = wC3;
        }
        __builtin_amdgcn_s_setprio(1);
        c0 = fmaf(blo(R00.x), f0, c0); c1 = fmaf(bhi(R00.x), f0, c1);
        c2 = fmaf(blo(R00.y), f0, c2); c3 = fmaf(bhi(R00.y), f0, c3);
        c0 = fmaf(blo(R01.x), f1, c0); c1 = fmaf(bhi(R01.x), f1, c1);
        c2 = fmaf(blo(R01.y), f1, c2); c3 = fmaf(bhi(R01.y), f1, c3);
        c0 = fmaf(blo(R02.x), f2, c0); c1 = fmaf(bhi(R02.x), f2, c1);
        c2 = fmaf(blo(R02.y), f2, c2); c3 = fmaf(bhi(R02.y), f2, c3);
        c0 = fmaf(blo(R03.x), f3, c0); c1 = fmaf(bhi(R03.x), f3, c1);
        c2 = fmaf(blo(R03.y), f3, c2); c3 = fmaf(bhi(R03.y), f3, c3);
        __builtin_amdgcn_s_setprio(0);
        R00 = R10; R01 = R11; R02 = R12; R03 = R13;
        R10 = R20; R11 = R21; R12 = R22; R13 = R23;
        wC0 = wB0; wC1 = wB1; wC2 = wB2; wC3 = wB3;
        wB0 = wA0; wB1 = wA1; wB2 = wA2; wB3 = wA3;
        wA0 = wN0; wA1 = wN1; wA2 = wN2; wA3 = wN3;
        j0 = k0; j1 = k1; j2 = k2; j3 = k3;
      }
    }
    if (GAT) { c0 *= fscale; c1 *= fscale; c2 *= fscale; c3 *= fscale; }
    ((uint2*)aggb)[(size_t)n * 32 + hl] = make_uint2(packh2(c0, c1), packh2(c2, c3));
    s0 += c0; s1 += c1; s2 += c2; s3 += c3;
    q0 += c0 * c0; q1 += c1 * c1; q2 += c2 * c2; q3 += c3 * c3;
  }
#undef LOADPK
  s0 += __shfl_xor(s0, 32); s1 += __shfl_xor(s1, 32);
  s2 += __shfl_xor(s2, 32); s3 += __shfl_xor(s3, 32);
  q0 += __shfl_xor(q0, 32); q1 += __shfl_xor(q1, 32);
  q2 += __shfl_xor(q2, 32); q3 += __shfl_xor(q3, 32);
  __shared__ float red[4][128];
  int w = tid >> 6;
  if (half == 0) {
    red[w][4 * hl + 0] = s0; red[w][4 * hl + 1] = s1;
    red[w][4 * hl + 2] = s2; red[w][4 * hl + 3] = s3;
  }
  __syncthreads();
  if (w == 0) {
    float a = red[0][2 * lane] + red[1][2 * lane] + red[2][2 * lane] + red[3][2 * lane];
    float b = red[0][2 * lane + 1] + red[1][2 * lane + 1] + red[2][2 * lane + 1] + red[3][2 * lane + 1];
    atomicAdd(&stats[2 * lane], a);
    atomicAdd(&stats[2 * lane + 1], b);
  }
  __syncthreads();
  if (half == 0) {
    red[w][4 * hl + 0] = q0; red[w][4 * hl + 1] = q1;
    red[w][4 * hl + 2] = q2; red[w][4 * hl + 3] = q3;
  }
  __syncthreads();
  if (w == 0) {
    float a = red[0][2 * lane] + red[1][2 * lane] + red[2][2 * lane] + red[3][2 * lane];
    float b = red[0][2 * lane + 1] + red[1][2 * lane + 1] + red[2][2 * lane + 1] + red[3][2 * lane + 1];
    atomicAdd(&stats[128 + 2 * lane], a);
    atomicAdd(&stats[128 + 2 * lane + 1], b);
  }
}

// ---------------- es/ed for GAT ----------------
__global__ __launch_bounds__(256) void compute_esed(const uint32_t* __restrict__ Hb,
                                                    const float* __restrict__ asrc,
                                                    const float* __restrict__ adst,
                                                    float* __restrict__ es, float* __restrict__ ed) {
  int lane = threadIdx.x & 63;
  int gwave = (blockIdx.x * 256 + threadIdx.x) >> 6;
  if (gwave >= N_NODES) return;
  float2 av = ((const float2*)asrc)[lane];
  float2 dv = ((const float2*)adst)[lane];
  uint32_t hv = Hb[(size_t)gwave * 64 + lane];
  float hx = blo(hv), hy = bhi(hv);
  float e_s = hx * av.x + hy * av.y;
  float e_d = hx * dv.x + hy * dv.y;
  for (int off = 32; off; off >>= 1) {
    e_s += __shfl_down(e_s, off);
    e_d += __shfl_down(e_d, off);
  }
  if (lane == 0) { es[gwave] = e_s; ed[gwave] = e_d; }
}

// overwrite pack.y: pads (y==0) -> -1e30 sentinel; else es[src]
__global__ void gat_pack_kernel(int2* __restrict__ sw, const float* __restrict__ es) {
  int e = blockIdx.x * 256 + threadIdx.x;
  if (e < CSR_CAP) {
    int2 v = sw[e];
    v.y = (v.y == 0) ? __float_as_int(-1e30f) : __float_as_int(es[v.x]);
    sw[e] = v;
  }
}

// ---------------- pooling with fused BN+ReLU+residual of last layer; bf16 out ----------------
__global__ void graph_starts(const int* __restrict__ batch, int* __restrict__ gstart) {
  int n = blockIdx.x * 256 + threadIdx.x;
  if (n >= N_NODES) return;
  int b = batch[n];
  int bp = (n == 0) ? -1 : batch[n - 1];
  for (int g = bp + 1; g <= b; ++g) gstart[g] = n;
  if (n == N_NODES - 1) {
    for (int g = b + 1; g <= BG; ++g) gstart[g] = N_NODES;
  }
}

__global__ __launch_bounds__(256) void pool_bn(const uint32_t* __restrict__ aggb,
                                               const uint32_t* __restrict__ xb,
                                               const float* __restrict__ stats,
                                               const float* __restrict__ gamma,
                                               const float* __restrict__ beta,
                                               const int* __restrict__ gstart,
                                               uint32_t* __restrict__ pooledb) {
  int g = blockIdx.x;
  int c = threadIdx.x & 127;
  int half = threadIdx.x >> 7;
  const float n_inv = 1.f / (float)N_NODES;
  float m = stats[c] * n_inv;
  float v = stats[128 + c] * n_inv - m * m;
  float sc = gamma[c] * rsqrtf(v + BN_EPS);
  float bc = beta[c] - m * sc;
  int s = gstart[g], e = gstart[g + 1];
  float acc = 0.f;
  for (int n = s + half; n < e; n += 2) {
    uint32_t aw = aggb[(size_t)n * 64 + (c >> 1)];
    float a = (c & 1) ? hhi(aw) : hlo(aw);
    uint32_t u = xb[(size_t)n * 64 + (c >> 1)];
    float xo = (c & 1) ? bhi(u) : blo(u);
    acc += fmaxf(fmaf(a, sc, bc), 0.f) + xo;
  }
  __shared__ float red[256];
  __shared__ float fin[128];
  red[threadIdx.x] = acc;
  __syncthreads();
  if (half == 0) {
    float vsum = red[c] + red[128 + c];
    int cnt = e - s;
    fin[c] = vsum / fmaxf((float)cnt, 1.f);
  }
  __syncthreads();
  if (half == 0 && !(c & 1))
    pooledb[(size_t)g * 64 + (c >> 1)] = pack2(fin[c], fin[c + 1]);
}

// ---------------- host launch ----------------
extern "C" void kernel_launch(void* const* d_in, const int* in_sizes, int n_in,
                              void* d_out, int out_size, void* d_ws, size_t ws_size,
                              hipStream_t stream) {
  const float* x_in  = (const float*)d_in[0];
  const int*   eidx  = (const int*)d_in[1];
  const int*   batch = (const int*)d_in[2];
  const float* W1 = (const float*)d_in[3];
  const float* g1 = (const float*)d_in[5];
  const float* be1 = (const float*)d_in[6];
  const float* W2 = (const float*)d_in[7];
  const float* g2 = (const float*)d_in[9];
  const float* be2 = (const float*)d_in[10];
  const float* W3 = (const float*)d_in[11];
  const float* g3 = (const float*)d_in[13];
  const float* be3 = (const float*)d_in[14];
  const float* Wa = (const float*)d_in[15];
  const float* asrc = (const float*)d_in[16];
  const float* adst = (const float*)d_in[17];
  const float* ga = (const float*)d_in[19];
  const float* bea = (const float*)d_in[20];
  const float* Wh1 = (const float*)d_in[21];
  const float* bh1 = (const float*)d_in[22];
  const float* Wm0 = (const float*)d_in[23];
  const float* bm0 = (const float*)d_in[24];
  const float* Wm1 = (const float*)d_in[25];
  const float* bm1 = (const float*)d_in[26];
  const float* Wo = (const float*)d_in[27];
  const float* bo = (const float*)d_in[28];

  const int* src = eidx;
  const int* dst = eidx + N_EDGES;

  char* p = (char*)d_ws;
  auto alloc = [&](size_t bytes) {
    char* r = p;
    p += (bytes + 255) & ~(size_t)255;
    return r;
  };
  // ---- zero-region (one memset): indeg+cursor, stats, gcnt+gcur, csr_sw ----
  char* zbase = p;
  int*   indeg     = (int*)alloc((size_t)2 * N_NODES * 4);  // indeg + cursor
  int*   cursor    = indeg + N_NODES;
  float* stats     = (float*)alloc(4 * 256 * 4);
  int*   gcnt      = (int*)alloc(128 * 4);                  // gcnt[64] + gcur[64]
  int*   gcur      = gcnt + 64;
  int2*  csr_sw    = (int2*)alloc((size_t)CSR_CAP * 8);
  size_t zsize = (size_t)(p - zbase);
  // ---- rest ----
  uint32_t* Hb     = (uint32_t*)alloc((size_t)N_NODES * 64 * 4);
  uint32_t* xb     = (uint32_t*)alloc((size_t)N_NODES * 64 * 4);
  uint32_t* aggb   = (uint32_t*)alloc((size_t)N_NODES * 64 * 4);   // fp16 pairs
  int*   rowstart  = (int*)alloc((size_t)(N_NODES + 1) * 4);
  int*   perm      = (int*)alloc((size_t)N_NODES * 4);
  float* dinv      = (float*)alloc((size_t)N_NODES * 4);
  float* es        = (float*)alloc((size_t)N_NODES * 4);
  float* ed        = (float*)alloc((size_t)N_NODES * 4);
  int*   chunksum  = (int*)alloc(128 * 4);
  int*   gstart    = (int*)alloc((BG + 1) * 4);
  uint32_t* pooledb = (uint32_t*)alloc((size_t)BG * 64 * 4);
  uint32_t* m1b    = (uint32_t*)alloc((size_t)BG * (NHID / 2) * 4);
  uint32_t* m2b    = (uint32_t*)alloc((size_t)BG * (NHID / 2) * 4);
  unsigned short* Wp1 = (unsigned short*)alloc(2048 * 8 * 2);
  unsigned short* Wp2 = (unsigned short*)alloc(2048 * 8 * 2);
  unsigned short* Wp3 = (unsigned short*)alloc(2048 * 8 * 2);
  unsigned short* Wp4 = (unsigned short*)alloc(2048 * 8 * 2);
  unsigned short* P1 = (unsigned short*)alloc((size_t)8192 * 8 * 2);
  unsigned short* P2 = (unsigned short*)alloc((size_t)32768 * 8 * 2);
  unsigned short* P3 = (unsigned short*)alloc((size_t)32768 * 8 * 2);
  unsigned short* P4 = (unsigned short*)alloc((size_t)16384 * 8 * 2);

  hipMemsetAsync(zbase, 0, zsize, stream);

  // CSR build (padded rows) + degree-matched permutation
  hist_kernel<<<(N_EDGES + 255) / 256, 256, 0, stream>>>(dst, indeg);
  scan_chunks<<<98, 256, 0, stream>>>(indeg, rowstart, chunksum);
  scan_finish<<<(N_NODES + 256) / 256, 256, 0, stream>>>(chunksum, rowstart, indeg, dinv, gcnt);
  scatter_perm<<<(N_NODES + 255) / 256, 256, 0, stream>>>(indeg, gcnt, gcur, perm);
  scatter_edges<<<(N_EDGES + 255) / 256, 256, 0, stream>>>(src, dst, rowstart, cursor, dinv, csr_sw);

  // prep: cast x + pack conv weights + pack MLP weights (single dispatch)
  prep_kernel<<<25032 + 352, 256, 0, stream>>>((const float2*)x_in, xb, W1, W2, W3, Wa,
                                               Wp1, Wp2, Wp3, Wp4,
                                               Wh1, Wm0, Wm1, Wo, P1, P2, P3, P4);
  graph_starts<<<(N_NODES + 255) / 256, 256, 0, stream>>>(batch, gstart);

  const int gemm_blocks_m = (N_NODES + 127) / 128;  // 782
  const int AGG_BLOCKS = 2048;

  // layer 1
  gemm_mfma<0><<<gemm_blocks_m, 256, 0, stream>>>(xb, nullptr, nullptr, nullptr, nullptr,
                                                  Wp1, Hb, N_NODES);
  agg_kernel<0><<<AGG_BLOCKS, 256, 0, stream>>>((const uint2*)Hb, rowstart, csr_sw, perm,
                                                dinv, indeg, nullptr, nullptr, aggb, stats + 0 * 256);
  // layer 2 (fuse BN1)
  gemm_mfma<1><<<gemm_blocks_m, 256, 0, stream>>>(xb, aggb, stats + 0 * 256, g1, be1,
                                                  Wp2, Hb, N_NODES);
  agg_kernel<0><<<AGG_BLOCKS, 256, 0, stream>>>((const uint2*)Hb, rowstart, csr_sw, perm,
                                                dinv, indeg, nullptr, nullptr, aggb, stats + 1 * 256);
  // layer 3 (fuse BN2)
  gemm_mfma<1><<<gemm_blocks_m, 256, 0, stream>>>(xb, aggb, stats + 1 * 256, g2, be2,
                                                  Wp3, Hb, N_NODES);
  agg_kernel<0><<<AGG_BLOCKS, 256, 0, stream>>>((const uint2*)Hb, rowstart, csr_sw, perm,
                                                dinv, indeg, nullptr, nullptr, aggb, stats + 2 * 256);
  // layer 4 = GAT (fuse BN3)
  gemm_mfma<1><<<gemm_blocks_m, 256, 0, stream>>>(xb, aggb, stats + 2 * 256, g3, be3,
                                                  Wp4, Hb, N_NODES);
  compute_esed<<<(N_NODES + 3) / 4, 256, 0, stream>>>(Hb, asrc, adst, es, ed);
  gat_pack_kernel<<<(CSR_CAP + 255) / 256, 256, 0, stream>>>(csr_sw, es);
  agg_kernel<1><<<AGG_BLOCKS, 256, 0, stream>>>((const uint2*)Hb, rowstart, csr_sw, perm,
                                                nullptr, indeg, es, ed, aggb, stats + 3 * 256);

  // pooling (fuses BN4), bf16 out
  pool_bn<<<BG, 256, 0, stream>>>(aggb, xb, stats + 3 * 256, ga, bea, gstart, pooledb);

  // MLP head (MFMA bf16)
  gemm_mlp<1, 0><<<dim3(4, 4), 256, 0, stream>>>(pooledb, P1, bh1, m1b, BG, CCH, NHID);
  gemm_mlp<1, 0><<<dim3(4, 4), 256, 0, stream>>>(m1b, P2, bm0, m2b, BG, NHID, NHID);
  gemm_mlp<1, 0><<<dim3(4, 4), 256, 0, stream>>>(m2b, P3, bm1, m1b, BG, NHID, NHID);
  gemm_mlp<0, 1><<<dim3(4, 2), 256, 0, stream>>>(m1b, P4, bo, d_out, BG, NHID, NOUT);
}

// Round 11
// 1020.580 us; speedup vs baseline: 2.1188x; 2.1188x over previous
//
#include <hip/hip_runtime.h>
#include <hip/hip_fp16.h>

// Problem constants (match reference)
#define N_NODES 100000
#define N_EDGES 1600000
#define CCH     128
#define BG      512
#define NHID    512
#define NOUT    256
#define BN_EPS  1e-5f
// padded CSR capacity: sum ceil(d/4)*4 <= E + 3N, +128 tail pad
#define CSR_CAP (N_EDGES + 4 * N_NODES + 128)

typedef __attribute__((ext_vector_type(8))) short s16x8;
typedef __attribute__((ext_vector_type(4))) float f32x4;

static __device__ __forceinline__ float leaky(float x) { return x > 0.f ? x : 0.2f * x; }
static __device__ __forceinline__ uint32_t bfr16(float x) {
  uint32_t u = __float_as_uint(x);
  u += 0x7fffu + ((u >> 16) & 1u);
  return u >> 16;
}
static __device__ __forceinline__ uint32_t pack2(float a, float b) {
  return bfr16(a) | (bfr16(b) << 16);
}
static __device__ __forceinline__ float blo(uint32_t u) { return __uint_as_float(u << 16); }
static __device__ __forceinline__ float bhi(uint32_t u) { return __uint_as_float(u & 0xffff0000u); }
static __device__ __forceinline__ uint32_t packh2(float a, float b) {
  __half2 h;
  h.x = __float2half(a);
  h.y = __float2half(b);
  return *reinterpret_cast<uint32_t*>(&h);
}
static __device__ __forceinline__ float hlo(uint32_t u) {
  __half2 h = *reinterpret_cast<__half2*>(&u);
  return __half2float(h.x);
}
static __device__ __forceinline__ float hhi(uint32_t u) {
  __half2 h = *reinterpret_cast<__half2*>(&u);
  return __half2float(h.y);
}

// ---------------- graph prep ----------------
__global__ void hist_kernel(const int* __restrict__ dst, int* __restrict__ indeg) {
  int e = blockIdx.x * 256 + threadIdx.x;
  if (e < N_EDGES) atomicAdd(&indeg[dst[e]], 1);
}

// scan over PADDED degrees (ceil(d/4)*4); 1024 elems/block
__global__ __launch_bounds__(256) void scan_chunks(const int* __restrict__ indeg,
                                                   int* __restrict__ rowstart,
                                                   int* __restrict__ chunksum) {
  int tid = threadIdx.x;
  int base = blockIdx.x * 1024 + tid * 4;
  int4 v;
  if (base + 3 < N_NODES) {
    v = *(const int4*)(indeg + base);
  } else {
    v.x = (base + 0 < N_NODES) ? indeg[base + 0] : 0;
    v.y = (base + 1 < N_NODES) ? indeg[base + 1] : 0;
    v.z = (base + 2 < N_NODES) ? indeg[base + 2] : 0;
    v.w = (base + 3 < N_NODES) ? indeg[base + 3] : 0;
  }
  int px = (v.x + 3) & ~3, py = (v.y + 3) & ~3, pz = (v.z + 3) & ~3, pw = (v.w + 3) & ~3;
  int s = px + py + pz + pw;
  __shared__ int ss[256];
  ss[tid] = s;
  __syncthreads();
  for (int off = 1; off < 256; off <<= 1) {
    int t = (tid >= off) ? ss[tid - off] : 0;
    __syncthreads();
    ss[tid] += t;
    __syncthreads();
  }
  int excl = ss[tid] - s;
  if (base + 0 < N_NODES) rowstart[base + 0] = excl;
  if (base + 1 < N_NODES) rowstart[base + 1] = excl + px;
  if (base + 2 < N_NODES) rowstart[base + 2] = excl + px + py;
  if (base + 3 < N_NODES) rowstart[base + 3] = excl + px + py + pz;
  if (tid == 255) chunksum[blockIdx.x] = ss[255];
}

// merged: chunk-prefix finalize + dinv
__global__ __launch_bounds__(256) void scan_finish(const int* __restrict__ chunksum,
                                                   int* __restrict__ rowstart,
                                                   const int* __restrict__ indeg,
                                                   float* __restrict__ dinv) {
  __shared__ int ss[128];
  __shared__ int ex[128];
  int tid = threadIdx.x;
  int v0 = 0;
  if (tid < 128) { v0 = (tid < 98) ? chunksum[tid] : 0; ss[tid] = v0; }
  __syncthreads();
  for (int off = 1; off < 128; off <<= 1) {
    int t = 0;
    if (tid < 128 && tid >= off) t = ss[tid - off];
    __syncthreads();
    if (tid < 128) ss[tid] += t;
    __syncthreads();
  }
  if (tid < 128) ex[tid] = ss[tid] - v0;   // exclusive chunk prefix
  __syncthreads();
  int i = blockIdx.x * 256 + tid;
  if (i < N_NODES) {
    rowstart[i] += ex[i >> 10];
    dinv[i] = rsqrtf((float)(indeg[i] + 1));
  } else if (i == N_NODES) {
    rowstart[N_NODES] = ss[97];
  }
}

__global__ void scatter_edges(const int* __restrict__ src, const int* __restrict__ dst,
                              const int* __restrict__ rowstart, int* __restrict__ cursor,
                              const float* __restrict__ dinv, int2* __restrict__ csr_sw) {
  int e = blockIdx.x * 256 + threadIdx.x;
  if (e < N_EDGES) {
    int d = dst[e];
    int s = src[e];
    int p = rowstart[d] + atomicAdd(&cursor[d], 1);
    float w = dinv[s] * dinv[d];   // > 0 always (pad sentinel relies on this)
    csr_sw[p] = make_int2(s, __float_as_int(w));
  }
}

// ---------------- prep: cast x + pack conv weights + pack MLP weights (one dispatch) ----
__global__ void prep_kernel(const float2* __restrict__ x2, uint32_t* __restrict__ xb,
                            const float* __restrict__ W1, const float* __restrict__ W2,
                            const float* __restrict__ W3, const float* __restrict__ W4,
                            unsigned short* __restrict__ Wp1, unsigned short* __restrict__ Wp2,
                            unsigned short* __restrict__ Wp3, unsigned short* __restrict__ Wp4,
                            const float* __restrict__ Wh1, const float* __restrict__ Wm0,
                            const float* __restrict__ Wm1, const float* __restrict__ Wo,
                            unsigned short* __restrict__ P1, unsigned short* __restrict__ P2,
                            unsigned short* __restrict__ P3, unsigned short* __restrict__ P4) {
  int b = blockIdx.x;
  if (b < 25000) {
    size_t idx = (size_t)b * 256 + threadIdx.x;
    float2 v = x2[idx];
    xb[idx] = pack2(v.x, v.y);
    return;
  }
  if (b < 25032) {
    int pb = b - 25000;
    int wsel = pb >> 3;
    int t = (pb & 7) * 256 + threadIdx.x;
    const float* W = (wsel == 0) ? W1 : (wsel == 1) ? W2 : (wsel == 2) ? W3 : W4;
    unsigned short* Wp = (wsel == 0) ? Wp1 : (wsel == 1) ? Wp2 : (wsel == 2) ? Wp3 : Wp4;
    int lane = t & 63;
    int ks = (t >> 6) & 3;
    int nt = t >> 8;
    int c = nt * 16 + (lane & 15);
    int kb = ks * 32 + (lane >> 4) * 8;
#pragma unroll
    for (int i = 0; i < 8; ++i)
      Wp[(size_t)t * 8 + i] = (unsigned short)bfr16(W[(size_t)(kb + i) * 128 + c]);
    return;
  }
  // MLP weight packing
  int t = (b - 25032) * 256 + threadIdx.x;
  const float* W;
  unsigned short* P;
  int K, N, loc;
  if (t < 8192)        { W = Wh1; P = P1; K = 128; N = 512; loc = t; }
  else if (t < 40960)  { W = Wm0; P = P2; K = 512; N = 512; loc = t - 8192; }
  else if (t < 73728)  { W = Wm1; P = P3; K = 512; N = 512; loc = t - 40960; }
  else if (t < 90112)  { W = Wo;  P = P4; K = 512; N = 256; loc = t - 73728; }
  else return;
  int ksn = K >> 5;
  int lane = loc & 63;
  int ks = (loc >> 6) & (ksn - 1);
  int nt = loc / (64 * ksn);
  int c = nt * 16 + (lane & 15);
  int kb = ks * 32 + (lane >> 4) * 8;
#pragma unroll
  for (int i = 0; i < 8; ++i)
    P[(size_t)loc * 8 + i] = (unsigned short)bfr16(W[(size_t)(kb + i) * N + c]);
}

// ---------------- MFMA conv GEMM, optionally fusing BN+ReLU+residual on the A side ------
template <int FUSE>
__global__ __launch_bounds__(256) void gemm_mfma(uint32_t* __restrict__ xbm,
                                                 const uint32_t* __restrict__ aggb,   // fp16 pairs
                                                 const float* __restrict__ stats,
                                                 const float* __restrict__ gamma,
                                                 const float* __restrict__ beta,
                                                 const unsigned short* __restrict__ Wp,
                                                 uint32_t* __restrict__ Hb,
                                                 int M) {
  __shared__ float scs[128], bcs[128];
  if (FUSE) {
    int t = threadIdx.x;
    if (t < 128) {
      const float n_inv = 1.f / (float)N_NODES;
      float m = stats[t] * n_inv;
      float v = stats[128 + t] * n_inv - m * m;
      float s = gamma[t] * rsqrtf(v + BN_EPS);
      scs[t] = s;
      bcs[t] = beta[t] - m * s;
    }
    __syncthreads();
  }
  int wave = threadIdx.x >> 6, lane = threadIdx.x & 63;
  int row0 = blockIdx.x * 128 + wave * 32;
  int r = lane & 15, g = lane >> 4;

  f32x4 acc[2][8];
#pragma unroll
  for (int mt = 0; mt < 2; ++mt)
#pragma unroll
    for (int nt = 0; nt < 8; ++nt) acc[mt][nt] = (f32x4){0.f, 0.f, 0.f, 0.f};

  s16x8 a[2][4];
#pragma unroll
  for (int mt = 0; mt < 2; ++mt) {
    int row = row0 + mt * 16 + r;
    bool v = row < M;
    if (FUSE) {
#pragma unroll
      for (int ks = 0; ks < 4; ++ks) {
        int ch = ks * 32 + g * 8;
        s16x8 af = {0, 0, 0, 0, 0, 0, 0, 0};
        if (v) {
          uint4 av4 = *(const uint4*)(aggb + (size_t)row * 64 + (ch >> 1));
          uint4 xo = *(const uint4*)(xbm + (size_t)row * 64 + (ch >> 1));
          float aa[8] = {hlo(av4.x), hhi(av4.x), hlo(av4.y), hhi(av4.y),
                         hlo(av4.z), hhi(av4.z), hlo(av4.w), hhi(av4.w)};
          float xold[8] = {blo(xo.x), bhi(xo.x), blo(xo.y), bhi(xo.y),
                           blo(xo.z), bhi(xo.z), blo(xo.w), bhi(xo.w)};
          uint32_t pk[4];
#pragma unroll
          for (int jj = 0; jj < 4; ++jj) {
            float r0v = fmaxf(fmaf(aa[2 * jj],     scs[ch + 2 * jj],     bcs[ch + 2 * jj]),     0.f) + xold[2 * jj];
            float r1v = fmaxf(fmaf(aa[2 * jj + 1], scs[ch + 2 * jj + 1], bcs[ch + 2 * jj + 1]), 0.f) + xold[2 * jj + 1];
            pk[jj] = pack2(r0v, r1v);
          }
          uint4 st = make_uint4(pk[0], pk[1], pk[2], pk[3]);
          *(uint4*)(xbm + (size_t)row * 64 + (ch >> 1)) = st;
          af = *(s16x8*)&st;
        }
        a[mt][ks] = af;
      }
    } else {
      const unsigned short* ap = (const unsigned short*)xbm + (size_t)row * 128 + g * 8;
#pragma unroll
      for (int ks = 0; ks < 4; ++ks) {
        s16x8 af = {0, 0, 0, 0, 0, 0, 0, 0};
        if (v) af = *(const s16x8*)(ap + ks * 32);
        a[mt][ks] = af;
      }
    }
  }
#pragma unroll
  for (int ks = 0; ks < 4; ++ks) {
#pragma unroll
    for (int nt = 0; nt < 8; ++nt) {
      s16x8 bfr = *(const s16x8*)(Wp + ((size_t)(nt * 4 + ks) * 64 + lane) * 8);
      acc[0][nt] = __builtin_amdgcn_mfma_f32_16x16x32_bf16(a[0][ks], bfr, acc[0][nt], 0, 0, 0);
      acc[1][nt] = __builtin_amdgcn_mfma_f32_16x16x32_bf16(a[1][ks], bfr, acc[1][nt], 0, 0, 0);
    }
  }
#pragma unroll
  for (int mt = 0; mt < 2; ++mt) {
#pragma unroll
    for (int nt = 0; nt < 8; ++nt) {
#pragma unroll
      for (int reg = 0; reg < 4; ++reg) {
        float v0 = acc[mt][nt][reg];
        float v1 = __shfl_xor(v0, 1);
        int row = row0 + mt * 16 + (lane >> 4) * 4 + reg;
        int col = nt * 16 + (lane & 15);
        if (!(lane & 1) && row < M)
          Hb[(size_t)row * 64 + (col >> 1)] = pack2(v0, v1);
      }
    }
  }
}

// ---------------- MLP MFMA GEMM ----------------
template <int RELU, int OUTF32>
__global__ __launch_bounds__(256) void gemm_mlp(const uint32_t* __restrict__ Ab,
                                                const unsigned short* __restrict__ Wp,
                                                const float* __restrict__ bias,
                                                void* __restrict__ outp,
                                                int M, int K, int N) {
  int wave = threadIdx.x >> 6, lane = threadIdx.x & 63;
  int row0 = blockIdx.x * 128 + wave * 32;
  int colb = blockIdx.y;
  const unsigned short* A16 = (const unsigned short*)Ab;
  int KS = K >> 5;
  int r = lane & 15, g = lane >> 4;
  f32x4 acc[2][8];
#pragma unroll
  for (int mt = 0; mt < 2; ++mt)
#pragma unroll
    for (int nt = 0; nt < 8; ++nt) acc[mt][nt] = (f32x4){0.f, 0.f, 0.f, 0.f};

  for (int ks = 0; ks < KS; ++ks) {
    s16x8 a[2];
#pragma unroll
    for (int mt = 0; mt < 2; ++mt) {
      int row = row0 + mt * 16 + r;
      s16x8 af = {0, 0, 0, 0, 0, 0, 0, 0};
      if (row < M) af = *(const s16x8*)(A16 + (size_t)row * K + ks * 32 + g * 8);
      a[mt] = af;
    }
#pragma unroll
    for (int ntl = 0; ntl < 8; ++ntl) {
      int ntg = colb * 8 + ntl;
      s16x8 b = *(const s16x8*)(Wp + ((size_t)(ntg * KS + ks) * 64 + lane) * 8);
      acc[0][ntl] = __builtin_amdgcn_mfma_f32_16x16x32_bf16(a[0], b, acc[0][ntl], 0, 0, 0);
      acc[1][ntl] = __builtin_amdgcn_mfma_f32_16x16x32_bf16(a[1], b, acc[1][ntl], 0, 0, 0);
    }
  }
#pragma unroll
  for (int mt = 0; mt < 2; ++mt) {
#pragma unroll
    for (int ntl = 0; ntl < 8; ++ntl) {
#pragma unroll
      for (int reg = 0; reg < 4; ++reg) {
        int row = row0 + mt * 16 + (lane >> 4) * 4 + reg;
        int col = colb * 128 + ntl * 16 + (lane & 15);
        float v0 = acc[mt][ntl][reg] + bias[col];
        if (RELU) v0 = fmaxf(v0, 0.f);
        if (OUTF32) {
          if (row < M) ((float*)outp)[(size_t)row * N + col] = v0;
        } else {
          float v1 = __shfl_xor(v0, 1);
          if (!(lane & 1) && row < M)
            ((uint32_t*)outp)[(size_t)row * (N >> 1) + (col >> 1)] = pack2(v0, v1);
        }
      }
    }
  }
}

// ---------------- unified aggregation: 2 nodes/wave, padded rows, depth-2 pipeline ----
template <int GAT>
__global__ __launch_bounds__(256) void agg_kernel(const uint2* __restrict__ Hb2,
                                                  const int* __restrict__ rowstart,
                                                  const int2* __restrict__ pack,
                                                  const float* __restrict__ dinv,
                                                  const int* __restrict__ indeg,
                                                  const float* __restrict__ es,
                                                  const float* __restrict__ ed,
                                                  uint32_t* __restrict__ aggb,
                                                  float* __restrict__ stats) {
  const float INVALW = GAT ? -1e30f : 0.0f;
  int tid = threadIdx.x;
  int lane = tid & 63;
  int hl = lane & 31;
  int half = lane >> 5;
  int gw = (blockIdx.x * 256 + tid) >> 6;
  int nw = (gridDim.x * 256) >> 6;
  float s0 = 0, s1 = 0, s2 = 0, s3 = 0, q0 = 0, q1 = 0, q2 = 0, q3 = 0;

#define LOADPK(gq, I0, I1, I2, I3, V0, V1, V2, V3)                        \
  do {                                                                    \
    bool ok = (gq) < G;                                                   \
    int ee = e0 + (gq) * 4;                                               \
    int2 pa = pack[ee], pb = pack[ee + 1], pc = pack[ee + 2], pd = pack[ee + 3]; \
    I0 = ok ? pa.x : 0; V0 = ok ? __int_as_float(pa.y) : INVALW;          \
    I1 = ok ? pb.x : 0; V1 = ok ? __int_as_float(pb.y) : INVALW;          \
    I2 = ok ? pc.x : 0; V2 = ok ? __int_as_float(pc.y) : INVALW;          \
    I3 = ok ? pd.x : 0; V3 = ok ? __int_as_float(pd.y) : INVALW;          \
  } while (0)

  for (int pi = gw; pi < N_NODES / 2; pi += nw) {
    int n = 2 * pi + half;
    int e0 = rowstart[n], e1p = rowstart[n + 1];
    int G = (e1p - e0) >> 2;
    int Gmax = max(G, __shfl_xor(G, 32));
    float edi = 0.f, selfw, fscale = 1.f;
    if (GAT) {
      int len = indeg[n];
      edi = ed[n];
      float wself = __expf(leaky(es[n] + edi));
      float wsum = (hl == 0) ? wself : 0.f;
      for (int e = e0 + hl; e < e0 + len; e += 32)
        wsum += __expf(leaky(__int_as_float(pack[e].y) + edi));
#pragma unroll
      for (int off = 16; off; off >>= 1) wsum += __shfl_xor(wsum, off);
      fscale = 1.f / (wsum + 1e-16f);
      selfw = wself;
    } else {
      float di = dinv[n];
      selfw = di * di;
    }
    uint2 hs = Hb2[(size_t)n * 32 + hl];
    float c0 = blo(hs.x) * selfw, c1 = bhi(hs.x) * selfw;
    float c2 = blo(hs.y) * selfw, c3 = bhi(hs.y) * selfw;

    if (Gmax > 0) {
      int j0, j1, j2, j3;
      float wC0, wC1, wC2, wC3;
      float wB0, wB1, wB2, wB3;
      float wA0, wA1, wA2, wA3;
      uint2 R00, R01, R02, R03;
      uint2 R10, R11, R12, R13;
      LOADPK(0, j0, j1, j2, j3, wC0, wC1, wC2, wC3);
      R00 = Hb2[(size_t)(unsigned)j0 * 32 + hl];
      R01 = Hb2[(size_t)(unsigned)j1 * 32 + hl];
      R02 = Hb2[(size_t)(unsigned)j2 * 32 + hl];
      R03 = Hb2[(size_t)(unsigned)j3 * 32 + hl];
      LOADPK(1, j0, j1, j2, j3, wB0, wB1, wB2, wB3);
      R10 = Hb2[(size_t)(unsigned)j0 * 32 + hl];
      R11 = Hb2[(size_t)(unsigned)j1 * 32 + hl];
      R12 = Hb2[(size_t)(unsigned)j2 * 32 + hl];
      R13 = Hb2[(size_t)(unsigned)j3 * 32 + hl];
      LOADPK(2, j0, j1, j2, j3, wA0, wA1, wA2, wA3);
      for (int g = 0; g < Gmax; ++g) {
        uint2 R20, R21, R22, R23;
        if (g + 2 < Gmax) {
          R20 = Hb2[(size_t)(unsigned)j0 * 32 + hl];
          R21 = Hb2[(size_t)(unsigned)j1 * 32 + hl];
          R22 = Hb2[(size_t)(unsigned)j2 * 32 + hl];
          R23 = Hb2[(size_t)(unsigned)j3 * 32 + hl];
        }
        int k0, k1, k2, k3;
        float wN0, wN1, wN2, wN3;
        if (g + 3 < Gmax) {
          LOADPK(g + 3, k0, k1, k2, k3, wN0, wN1, wN2, wN3);
        } else {
          k0 = k1 = k2 = k3 = 0;
          wN0 = wN1 = wN2 = wN3 = INVALW;
        }
        float f0, f1, f2, f3;
        if (GAT) {
          f0 = __expf(leaky(wC0 + edi)); f1 = __expf(leaky(wC1 + edi));
          f2 = __expf(leaky(wC2 + edi)); f3 = __expf(leaky(wC3 + edi));
        } else {
          f0 = wC0; f1 = wC1; f2 = wC2; f3 = wC3;
        }
        __builtin_amdgcn_s_setprio(1);
        c0 = fmaf(blo(R00.x), f0, c0); c1 = fmaf(bhi(R00.x), f0, c1);
        c2 = fmaf(blo(R00.y), f0, c2); c3 = fmaf(bhi(R00.y), f0, c3);
        c0 = fmaf(blo(R01.x), f1, c0); c1 = fmaf(bhi(R01.x), f1, c1);
        c2 = fmaf(blo(R01.y), f1, c2); c3 = fmaf(bhi(R01.y), f1, c3);
        c0 = fmaf(blo(R02.x), f2, c0); c1 = fmaf(bhi(R02.x), f2, c1);
        c2 = fmaf(blo(R02.y), f2, c2); c3 = fmaf(bhi(R02.y), f2, c3);
        c0 = fmaf(blo(R03.x), f3, c0); c1 = fmaf(bhi(R03.x), f3, c1);
        c2 = fmaf(blo(R03.y), f3, c2); c3 = fmaf(bhi(R03.y), f3, c3);
        __builtin_amdgcn_s_setprio(0);
        R00 = R10; R01 = R11; R02 = R12; R03 = R13;
        R10 = R20; R11 = R21; R12 = R22; R13 = R23;
        wC0 = wB0; wC1 = wB1; wC2 = wB2; wC3 = wB3;
        wB0 = wA0; wB1 = wA1; wB2 = wA2; wB3 = wA3;
        wA0 = wN0; wA1 = wN1; wA2 = wN2; wA3 = wN3;
        j0 = k0; j1 = k1; j2 = k2; j3 = k3;
      }
    }
    if (GAT) { c0 *= fscale; c1 *= fscale; c2 *= fscale; c3 *= fscale; }
    ((uint2*)aggb)[(size_t)n * 32 + hl] = make_uint2(packh2(c0, c1), packh2(c2, c3));
    s0 += c0; s1 += c1; s2 += c2; s3 += c3;
    q0 += c0 * c0; q1 += c1 * c1; q2 += c2 * c2; q3 += c3 * c3;
  }
#undef LOADPK
  s0 += __shfl_xor(s0, 32); s1 += __shfl_xor(s1, 32);
  s2 += __shfl_xor(s2, 32); s3 += __shfl_xor(s3, 32);
  q0 += __shfl_xor(q0, 32); q1 += __shfl_xor(q1, 32);
  q2 += __shfl_xor(q2, 32); q3 += __shfl_xor(q3, 32);
  __shared__ float red[4][128];
  int w = tid >> 6;
  if (half == 0) {
    red[w][4 * hl + 0] = s0; red[w][4 * hl + 1] = s1;
    red[w][4 * hl + 2] = s2; red[w][4 * hl + 3] = s3;
  }
  __syncthreads();
  if (w == 0) {
    float a = red[0][2 * lane] + red[1][2 * lane] + red[2][2 * lane] + red[3][2 * lane];
    float b = red[0][2 * lane + 1] + red[1][2 * lane + 1] + red[2][2 * lane + 1] + red[3][2 * lane + 1];
    atomicAdd(&stats[2 * lane], a);
    atomicAdd(&stats[2 * lane + 1], b);
  }
  __syncthreads();
  if (half == 0) {
    red[w][4 * hl + 0] = q0; red[w][4 * hl + 1] = q1;
    red[w][4 * hl + 2] = q2; red[w][4 * hl + 3] = q3;
  }
  __syncthreads();
  if (w == 0) {
    float a = red[0][2 * lane] + red[1][2 * lane] + red[2][2 * lane] + red[3][2 * lane];
    float b = red[0][2 * lane + 1] + red[1][2 * lane + 1] + red[2][2 * lane + 1] + red[3][2 * lane + 1];
    atomicAdd(&stats[128 + 2 * lane], a);
    atomicAdd(&stats[128 + 2 * lane + 1], b);
  }
}

// ---------------- es/ed for GAT ----------------
__global__ __launch_bounds__(256) void compute_esed(const uint32_t* __restrict__ Hb,
                                                    const float* __restrict__ asrc,
                                                    const float* __restrict__ adst,
                                                    float* __restrict__ es, float* __restrict__ ed) {
  int lane = threadIdx.x & 63;
  int gwave = (blockIdx.x * 256 + threadIdx.x) >> 6;
  if (gwave >= N_NODES) return;
  float2 av = ((const float2*)asrc)[lane];
  float2 dv = ((const float2*)adst)[lane];
  uint32_t hv = Hb[(size_t)gwave * 64 + lane];
  float hx = blo(hv), hy = bhi(hv);
  float e_s = hx * av.x + hy * av.y;
  float e_d = hx * dv.x + hy * dv.y;
  for (int off = 32; off; off >>= 1) {
    e_s += __shfl_down(e_s, off);
    e_d += __shfl_down(e_d, off);
  }
  if (lane == 0) { es[gwave] = e_s; ed[gwave] = e_d; }
}

// overwrite pack.y: pads (y==0) -> -1e30 sentinel; else es[src]
__global__ void gat_pack_kernel(int2* __restrict__ sw, const float* __restrict__ es) {
  int e = blockIdx.x * 256 + threadIdx.x;
  if (e < CSR_CAP) {
    int2 v = sw[e];
    v.y = (v.y == 0) ? __float_as_int(-1e30f) : __float_as_int(es[v.x]);
    sw[e] = v;
  }
}

// ---------------- pooling with fused BN+ReLU+residual of last layer; bf16 out ----------------
__global__ void graph_starts(const int* __restrict__ batch, int* __restrict__ gstart) {
  int n = blockIdx.x * 256 + threadIdx.x;
  if (n >= N_NODES) return;
  int b = batch[n];
  int bp = (n == 0) ? -1 : batch[n - 1];
  for (int g = bp + 1; g <= b; ++g) gstart[g] = n;
  if (n == N_NODES - 1) {
    for (int g = b + 1; g <= BG; ++g) gstart[g] = N_NODES;
  }
}

__global__ __launch_bounds__(256) void pool_bn(const uint32_t* __restrict__ aggb,
                                               const uint32_t* __restrict__ xb,
                                               const float* __restrict__ stats,
                                               const float* __restrict__ gamma,
                                               const float* __restrict__ beta,
                                               const int* __restrict__ gstart,
                                               uint32_t* __restrict__ pooledb) {
  int g = blockIdx.x;
  int c = threadIdx.x & 127;
  int half = threadIdx.x >> 7;
  const float n_inv = 1.f / (float)N_NODES;
  float m = stats[c] * n_inv;
  float v = stats[128 + c] * n_inv - m * m;
  float sc = gamma[c] * rsqrtf(v + BN_EPS);
  float bc = beta[c] - m * sc;
  int s = gstart[g], e = gstart[g + 1];
  float acc = 0.f;
  for (int n = s + half; n < e; n += 2) {
    uint32_t aw = aggb[(size_t)n * 64 + (c >> 1)];
    float a = (c & 1) ? hhi(aw) : hlo(aw);
    uint32_t u = xb[(size_t)n * 64 + (c >> 1)];
    float xo = (c & 1) ? bhi(u) : blo(u);
    acc += fmaxf(fmaf(a, sc, bc), 0.f) + xo;
  }
  __shared__ float red[256];
  __shared__ float fin[128];
  red[threadIdx.x] = acc;
  __syncthreads();
  if (half == 0) {
    float vsum = red[c] + red[128 + c];
    int cnt = e - s;
    fin[c] = vsum / fmaxf((float)cnt, 1.f);
  }
  __syncthreads();
  if (half == 0 && !(c & 1))
    pooledb[(size_t)g * 64 + (c >> 1)] = pack2(fin[c], fin[c + 1]);
}

// ---------------- host launch ----------------
extern "C" void kernel_launch(void* const* d_in, const int* in_sizes, int n_in,
                              void* d_out, int out_size, void* d_ws, size_t ws_size,
                              hipStream_t stream) {
  const float* x_in  = (const float*)d_in[0];
  const int*   eidx  = (const int*)d_in[1];
  const int*   batch = (const int*)d_in[2];
  const float* W1 = (const float*)d_in[3];
  const float* g1 = (const float*)d_in[5];
  const float* be1 = (const float*)d_in[6];
  const float* W2 = (const float*)d_in[7];
  const float* g2 = (const float*)d_in[9];
  const float* be2 = (const float*)d_in[10];
  const float* W3 = (const float*)d_in[11];
  const float* g3 = (const float*)d_in[13];
  const float* be3 = (const float*)d_in[14];
  const float* Wa = (const float*)d_in[15];
  const float* asrc = (const float*)d_in[16];
  const float* adst = (const float*)d_in[17];
  const float* ga = (const float*)d_in[19];
  const float* bea = (const float*)d_in[20];
  const float* Wh1 = (const float*)d_in[21];
  const float* bh1 = (const float*)d_in[22];
  const float* Wm0 = (const float*)d_in[23];
  const float* bm0 = (const float*)d_in[24];
  const float* Wm1 = (const float*)d_in[25];
  const float* bm1 = (const float*)d_in[26];
  const float* Wo = (const float*)d_in[27];
  const float* bo = (const float*)d_in[28];

  const int* src = eidx;
  const int* dst = eidx + N_EDGES;

  char* p = (char*)d_ws;
  auto alloc = [&](size_t bytes) {
    char* r = p;
    p += (bytes + 255) & ~(size_t)255;
    return r;
  };
  // ---- zero-region (one memset): indeg+cursor, stats, csr_sw ----
  char* zbase = p;
  int*   indeg     = (int*)alloc((size_t)2 * N_NODES * 4);  // indeg + cursor
  int*   cursor    = indeg + N_NODES;
  float* stats     = (float*)alloc(4 * 256 * 4);
  int2*  csr_sw    = (int2*)alloc((size_t)CSR_CAP * 8);
  size_t zsize = (size_t)(p - zbase);
  // ---- rest ----
  uint32_t* Hb     = (uint32_t*)alloc((size_t)N_NODES * 64 * 4);
  uint32_t* xb     = (uint32_t*)alloc((size_t)N_NODES * 64 * 4);
  uint32_t* aggb   = (uint32_t*)alloc((size_t)N_NODES * 64 * 4);   // fp16 pairs
  int*   rowstart  = (int*)alloc((size_t)(N_NODES + 1) * 4);
  float* dinv      = (float*)alloc((size_t)N_NODES * 4);
  float* es        = (float*)alloc((size_t)N_NODES * 4);
  float* ed        = (float*)alloc((size_t)N_NODES * 4);
  int*   chunksum  = (int*)alloc(128 * 4);
  int*   gstart    = (int*)alloc((BG + 1) * 4);
  uint32_t* pooledb = (uint32_t*)alloc((size_t)BG * 64 * 4);
  uint32_t* m1b    = (uint32_t*)alloc((size_t)BG * (NHID / 2) * 4);
  uint32_t* m2b    = (uint32_t*)alloc((size_t)BG * (NHID / 2) * 4);
  unsigned short* Wp1 = (unsigned short*)alloc(2048 * 8 * 2);
  unsigned short* Wp2 = (unsigned short*)alloc(2048 * 8 * 2);
  unsigned short* Wp3 = (unsigned short*)alloc(2048 * 8 * 2);
  unsigned short* Wp4 = (unsigned short*)alloc(2048 * 8 * 2);
  unsigned short* P1 = (unsigned short*)alloc((size_t)8192 * 8 * 2);
  unsigned short* P2 = (unsigned short*)alloc((size_t)32768 * 8 * 2);
  unsigned short* P3 = (unsigned short*)alloc((size_t)32768 * 8 * 2);
  unsigned short* P4 = (unsigned short*)alloc((size_t)16384 * 8 * 2);

  hipMemsetAsync(zbase, 0, zsize, stream);

  // CSR build (padded rows)
  hist_kernel<<<(N_EDGES + 255) / 256, 256, 0, stream>>>(dst, indeg);
  scan_chunks<<<98, 256, 0, stream>>>(indeg, rowstart, chunksum);
  scan_finish<<<(N_NODES + 256) / 256, 256, 0, stream>>>(chunksum, rowstart, indeg, dinv);
  scatter_edges<<<(N_EDGES + 255) / 256, 256, 0, stream>>>(src, dst, rowstart, cursor, dinv, csr_sw);

  // prep: cast x + pack conv weights + pack MLP weights (single dispatch)
  prep_kernel<<<25032 + 352, 256, 0, stream>>>((const float2*)x_in, xb, W1, W2, W3, Wa,
                                               Wp1, Wp2, Wp3, Wp4,
                                               Wh1, Wm0, Wm1, Wo, P1, P2, P3, P4);
  graph_starts<<<(N_NODES + 255) / 256, 256, 0, stream>>>(batch, gstart);

  const int gemm_blocks_m = (N_NODES + 127) / 128;  // 782
  const int AGG_BLOCKS = 2048;

  // layer 1
  gemm_mfma<0><<<gemm_blocks_m, 256, 0, stream>>>(xb, nullptr, nullptr, nullptr, nullptr,
                                                  Wp1, Hb, N_NODES);
  agg_kernel<0><<<AGG_BLOCKS, 256, 0, stream>>>((const uint2*)Hb, rowstart, csr_sw,
                                                dinv, indeg, nullptr, nullptr, aggb, stats + 0 * 256);
  // layer 2 (fuse BN1)
  gemm_mfma<1><<<gemm_blocks_m, 256, 0, stream>>>(xb, aggb, stats + 0 * 256, g1, be1,
                                                  Wp2, Hb, N_NODES);
  agg_kernel<0><<<AGG_BLOCKS, 256, 0, stream>>>((const uint2*)Hb, rowstart, csr_sw,
                                                dinv, indeg, nullptr, nullptr, aggb, stats + 1 * 256);
  // layer 3 (fuse BN2)
  gemm_mfma<1><<<gemm_blocks_m, 256, 0, stream>>>(xb, aggb, stats + 1 * 256, g2, be2,
                                                  Wp3, Hb, N_NODES);
  agg_kernel<0><<<AGG_BLOCKS, 256, 0, stream>>>((const uint2*)Hb, rowstart, csr_sw,
                                                dinv, indeg, nullptr, nullptr, aggb, stats + 2 * 256);
  // layer 4 = GAT (fuse BN3)
  gemm_mfma<1><<<gemm_blocks_m, 256, 0, stream>>>(xb, aggb, stats + 2 * 256, g3, be3,
                                                  Wp4, Hb, N_NODES);
  compute_esed<<<(N_NODES + 3) / 4, 256, 0, stream>>>(Hb, asrc, adst, es, ed);
  gat_pack_kernel<<<(CSR_CAP + 255) / 256, 256, 0, stream>>>(csr_sw, es);
  agg_kernel<1><<<AGG_BLOCKS, 256, 0, stream>>>((const uint2*)Hb, rowstart, csr_sw,
                                                nullptr, indeg, es, ed, aggb, stats + 3 * 256);

  // pooling (fuses BN4), bf16 out
  pool_bn<<<BG, 256, 0, stream>>>(aggb, xb, stats + 3 * 256, ga, bea, gstart, pooledb);

  // MLP head (MFMA bf16)
  gemm_mlp<1, 0><<<dim3(4, 4), 256, 0, stream>>>(pooledb, P1, bh1, m1b, BG, CCH, NHID);
  gemm_mlp<1, 0><<<dim3(4, 4), 256, 0, stream>>>(m1b, P2, bm0, m2b, BG, NHID, NHID);
  gemm_mlp<1, 0><<<dim3(4, 4), 256, 0, stream>>>(m2b, P3, bm1, m1b, BG, NHID, NHID);
  gemm_mlp<0, 1><<<dim3(4, 2), 256, 0, stream>>>(m1b, P4, bo, d_out, BG, NHID, NOUT);
}

// Round 12
// 1012.264 us; speedup vs baseline: 2.1362x; 1.0082x over previous
//
#include <hip/hip_runtime.h>
#include <hip/hip_fp16.h>

// Problem constants (match reference)
#define N_NODES 100000
#define N_EDGES 1600000
#define CCH     128
#define BG      512
#define NHID    512
#define NOUT    256
#define BN_EPS  1e-5f
// padded CSR capacity: sum ceil(d/4)*4 <= E + 3N, +128 tail pad (overread slack)
#define CSR_CAP (N_EDGES + 4 * N_NODES + 128)

typedef __attribute__((ext_vector_type(8))) short s16x8;
typedef __attribute__((ext_vector_type(4))) float f32x4;

static __device__ __forceinline__ float leaky(float x) { return x > 0.f ? x : 0.2f * x; }
static __device__ __forceinline__ uint32_t bfr16(float x) {
  uint32_t u = __float_as_uint(x);
  u += 0x7fffu + ((u >> 16) & 1u);
  return u >> 16;
}
static __device__ __forceinline__ uint32_t pack2(float a, float b) {
  return bfr16(a) | (bfr16(b) << 16);
}
static __device__ __forceinline__ float blo(uint32_t u) { return __uint_as_float(u << 16); }
static __device__ __forceinline__ float bhi(uint32_t u) { return __uint_as_float(u & 0xffff0000u); }
static __device__ __forceinline__ uint32_t packh2(float a, float b) {
  __half2 h;
  h.x = __float2half(a);
  h.y = __float2half(b);
  return *reinterpret_cast<uint32_t*>(&h);
}
static __device__ __forceinline__ float hlo(uint32_t u) {
  __half2 h = *reinterpret_cast<__half2*>(&u);
  return __half2float(h.x);
}
static __device__ __forceinline__ float hhi(uint32_t u) {
  __half2 h = *reinterpret_cast<__half2*>(&u);
  return __half2float(h.y);
}

// ---------------- graph prep ----------------
__global__ void hist_kernel(const int* __restrict__ dst, int* __restrict__ indeg) {
  int e = blockIdx.x * 256 + threadIdx.x;
  if (e < N_EDGES) atomicAdd(&indeg[dst[e]], 1);
}

// scan over PADDED degrees (ceil(d/4)*4); 1024 elems/block
__global__ __launch_bounds__(256) void scan_chunks(const int* __restrict__ indeg,
                                                   int* __restrict__ rowstart,
                                                   int* __restrict__ chunksum) {
  int tid = threadIdx.x;
  int base = blockIdx.x * 1024 + tid * 4;
  int4 v;
  if (base + 3 < N_NODES) {
    v = *(const int4*)(indeg + base);
  } else {
    v.x = (base + 0 < N_NODES) ? indeg[base + 0] : 0;
    v.y = (base + 1 < N_NODES) ? indeg[base + 1] : 0;
    v.z = (base + 2 < N_NODES) ? indeg[base + 2] : 0;
    v.w = (base + 3 < N_NODES) ? indeg[base + 3] : 0;
  }
  int px = (v.x + 3) & ~3, py = (v.y + 3) & ~3, pz = (v.z + 3) & ~3, pw = (v.w + 3) & ~3;
  int s = px + py + pz + pw;
  __shared__ int ss[256];
  ss[tid] = s;
  __syncthreads();
  for (int off = 1; off < 256; off <<= 1) {
    int t = (tid >= off) ? ss[tid - off] : 0;
    __syncthreads();
    ss[tid] += t;
    __syncthreads();
  }
  int excl = ss[tid] - s;
  if (base + 0 < N_NODES) rowstart[base + 0] = excl;
  if (base + 1 < N_NODES) rowstart[base + 1] = excl + px;
  if (base + 2 < N_NODES) rowstart[base + 2] = excl + px + py;
  if (base + 3 < N_NODES) rowstart[base + 3] = excl + px + py + pz;
  if (tid == 255) chunksum[blockIdx.x] = ss[255];
}

// merged: chunk-prefix finalize + dinv + zero the intra-row pad slots of csr_sw
__global__ __launch_bounds__(256) void scan_finish(const int* __restrict__ chunksum,
                                                   int* __restrict__ rowstart,
                                                   const int* __restrict__ indeg,
                                                   float* __restrict__ dinv,
                                                   int2* __restrict__ csr_sw) {
  __shared__ int ss[128];
  __shared__ int ex[128];
  int tid = threadIdx.x;
  int v0 = 0;
  if (tid < 128) { v0 = (tid < 98) ? chunksum[tid] : 0; ss[tid] = v0; }
  __syncthreads();
  for (int off = 1; off < 128; off <<= 1) {
    int t = 0;
    if (tid < 128 && tid >= off) t = ss[tid - off];
    __syncthreads();
    if (tid < 128) ss[tid] += t;
    __syncthreads();
  }
  if (tid < 128) ex[tid] = ss[tid] - v0;   // exclusive chunk prefix
  __syncthreads();
  int i = blockIdx.x * 256 + tid;
  if (i < N_NODES) {
    int r = rowstart[i] + ex[i >> 10];
    rowstart[i] = r;
    int d = indeg[i];
    dinv[i] = rsqrtf((float)(d + 1));
    int pd = (d + 3) & ~3;
    for (int e = r + d; e < r + pd; ++e) csr_sw[e] = make_int2(0, 0);  // pad slots
  } else if (i == N_NODES) {
    rowstart[N_NODES] = ss[97];
  }
}

__global__ void scatter_edges(const int* __restrict__ src, const int* __restrict__ dst,
                              const int* __restrict__ rowstart, int* __restrict__ cursor,
                              const float* __restrict__ dinv, int2* __restrict__ csr_sw) {
  int e = blockIdx.x * 256 + threadIdx.x;
  if (e < N_EDGES) {
    int d = dst[e];
    int s = src[e];
    int p = rowstart[d] + atomicAdd(&cursor[d], 1);
    float w = dinv[s] * dinv[d];   // > 0 always (pad sentinel relies on this)
    csr_sw[p] = make_int2(s, __float_as_int(w));
  }
}

// ---------------- prep: cast x + pack conv W + pack MLP W + graph_starts (one dispatch) ----
__global__ void prep_kernel(const float2* __restrict__ x2, uint32_t* __restrict__ xb,
                            const float* __restrict__ W1, const float* __restrict__ W2,
                            const float* __restrict__ W3, const float* __restrict__ W4,
                            unsigned short* __restrict__ Wp1, unsigned short* __restrict__ Wp2,
                            unsigned short* __restrict__ Wp3, unsigned short* __restrict__ Wp4,
                            const float* __restrict__ Wh1, const float* __restrict__ Wm0,
                            const float* __restrict__ Wm1, const float* __restrict__ Wo,
                            unsigned short* __restrict__ P1, unsigned short* __restrict__ P2,
                            unsigned short* __restrict__ P3, unsigned short* __restrict__ P4,
                            const int* __restrict__ batch, int* __restrict__ gstart) {
  int b = blockIdx.x;
  if (b < 25000) {
    size_t idx = (size_t)b * 256 + threadIdx.x;
    float2 v = x2[idx];
    xb[idx] = pack2(v.x, v.y);
    return;
  }
  if (b < 25032) {
    int pb = b - 25000;
    int wsel = pb >> 3;
    int t = (pb & 7) * 256 + threadIdx.x;
    const float* W = (wsel == 0) ? W1 : (wsel == 1) ? W2 : (wsel == 2) ? W3 : W4;
    unsigned short* Wp = (wsel == 0) ? Wp1 : (wsel == 1) ? Wp2 : (wsel == 2) ? Wp3 : Wp4;
    int lane = t & 63;
    int ks = (t >> 6) & 3;
    int nt = t >> 8;
    int c = nt * 16 + (lane & 15);
    int kb = ks * 32 + (lane >> 4) * 8;
#pragma unroll
    for (int i = 0; i < 8; ++i)
      Wp[(size_t)t * 8 + i] = (unsigned short)bfr16(W[(size_t)(kb + i) * 128 + c]);
    return;
  }
  if (b < 25384) {
    // MLP weight packing
    int t = (b - 25032) * 256 + threadIdx.x;
    const float* W;
    unsigned short* P;
    int K, N, loc;
    if (t < 8192)        { W = Wh1; P = P1; K = 128; N = 512; loc = t; }
    else if (t < 40960)  { W = Wm0; P = P2; K = 512; N = 512; loc = t - 8192; }
    else if (t < 73728)  { W = Wm1; P = P3; K = 512; N = 512; loc = t - 40960; }
    else if (t < 90112)  { W = Wo;  P = P4; K = 512; N = 256; loc = t - 73728; }
    else return;
    int ksn = K >> 5;
    int lane = loc & 63;
    int ks = (loc >> 6) & (ksn - 1);
    int nt = loc / (64 * ksn);
    int c = nt * 16 + (lane & 15);
    int kb = ks * 32 + (lane >> 4) * 8;
#pragma unroll
    for (int i = 0; i < 8; ++i)
      P[(size_t)loc * 8 + i] = (unsigned short)bfr16(W[(size_t)(kb + i) * N + c]);
    return;
  }
  // graph_starts
  int n = (b - 25384) * 256 + threadIdx.x;
  if (n >= N_NODES) return;
  int bb = batch[n];
  int bp = (n == 0) ? -1 : batch[n - 1];
  for (int g = bp + 1; g <= bb; ++g) gstart[g] = n;
  if (n == N_NODES - 1) {
    for (int g = bb + 1; g <= BG; ++g) gstart[g] = N_NODES;
  }
}

// ---------------- MFMA conv GEMM, fusing BN+ReLU+residual (FUSE) and es/ed (ESED) ------
template <int FUSE, int ESED>
__global__ __launch_bounds__(256) void gemm_mfma(uint32_t* __restrict__ xbm,
                                                 const uint32_t* __restrict__ aggb,   // fp16 pairs
                                                 const float* __restrict__ stats,
                                                 const float* __restrict__ gamma,
                                                 const float* __restrict__ beta,
                                                 const unsigned short* __restrict__ Wp,
                                                 uint32_t* __restrict__ Hb,
                                                 const float* __restrict__ asrc,
                                                 const float* __restrict__ adst,
                                                 float* __restrict__ es,
                                                 float* __restrict__ ed,
                                                 int M) {
  __shared__ float scs[128], bcs[128];
  __shared__ float sas[128], sad[128];
  {
    int t = threadIdx.x;
    if (FUSE && t < 128) {
      const float n_inv = 1.f / (float)N_NODES;
      float m = stats[t] * n_inv;
      float v = stats[128 + t] * n_inv - m * m;
      float s = gamma[t] * rsqrtf(v + BN_EPS);
      scs[t] = s;
      bcs[t] = beta[t] - m * s;
    }
    if (ESED && t >= 128 && t < 256) {
      sas[t - 128] = asrc[t - 128];
      sad[t - 128] = adst[t - 128];
    }
    if (FUSE || ESED) __syncthreads();
  }
  int wave = threadIdx.x >> 6, lane = threadIdx.x & 63;
  int row0 = blockIdx.x * 128 + wave * 32;
  int r = lane & 15, g = lane >> 4;

  f32x4 acc[2][8];
#pragma unroll
  for (int mt = 0; mt < 2; ++mt)
#pragma unroll
    for (int nt = 0; nt < 8; ++nt) acc[mt][nt] = (f32x4){0.f, 0.f, 0.f, 0.f};

  s16x8 a[2][4];
#pragma unroll
  for (int mt = 0; mt < 2; ++mt) {
    int row = row0 + mt * 16 + r;
    bool v = row < M;
    if (FUSE) {
#pragma unroll
      for (int ks = 0; ks < 4; ++ks) {
        int ch = ks * 32 + g * 8;
        s16x8 af = {0, 0, 0, 0, 0, 0, 0, 0};
        if (v) {
          uint4 av4 = *(const uint4*)(aggb + (size_t)row * 64 + (ch >> 1));
          uint4 xo = *(const uint4*)(xbm + (size_t)row * 64 + (ch >> 1));
          float aa[8] = {hlo(av4.x), hhi(av4.x), hlo(av4.y), hhi(av4.y),
                         hlo(av4.z), hhi(av4.z), hlo(av4.w), hhi(av4.w)};
          float xold[8] = {blo(xo.x), bhi(xo.x), blo(xo.y), bhi(xo.y),
                           blo(xo.z), bhi(xo.z), blo(xo.w), bhi(xo.w)};
          uint32_t pk[4];
#pragma unroll
          for (int jj = 0; jj < 4; ++jj) {
            float r0v = fmaxf(fmaf(aa[2 * jj],     scs[ch + 2 * jj],     bcs[ch + 2 * jj]),     0.f) + xold[2 * jj];
            float r1v = fmaxf(fmaf(aa[2 * jj + 1], scs[ch + 2 * jj + 1], bcs[ch + 2 * jj + 1]), 0.f) + xold[2 * jj + 1];
            pk[jj] = pack2(r0v, r1v);
          }
          uint4 st = make_uint4(pk[0], pk[1], pk[2], pk[3]);
          *(uint4*)(xbm + (size_t)row * 64 + (ch >> 1)) = st;
          af = *(s16x8*)&st;
        }
        a[mt][ks] = af;
      }
    } else {
      const unsigned short* ap = (const unsigned short*)xbm + (size_t)row * 128 + g * 8;
#pragma unroll
      for (int ks = 0; ks < 4; ++ks) {
        s16x8 af = {0, 0, 0, 0, 0, 0, 0, 0};
        if (v) af = *(const s16x8*)(ap + ks * 32);
        a[mt][ks] = af;
      }
    }
  }
#pragma unroll
  for (int ks = 0; ks < 4; ++ks) {
#pragma unroll
    for (int nt = 0; nt < 8; ++nt) {
      s16x8 bfr = *(const s16x8*)(Wp + ((size_t)(nt * 4 + ks) * 64 + lane) * 8);
      acc[0][nt] = __builtin_amdgcn_mfma_f32_16x16x32_bf16(a[0][ks], bfr, acc[0][nt], 0, 0, 0);
      acc[1][nt] = __builtin_amdgcn_mfma_f32_16x16x32_bf16(a[1][ks], bfr, acc[1][nt], 0, 0, 0);
    }
  }
  // epilogue: Hb write (+ optional fused es/ed)
#pragma unroll
  for (int mt = 0; mt < 2; ++mt) {
#pragma unroll
    for (int reg = 0; reg < 4; ++reg) {
      int row = row0 + mt * 16 + (lane >> 4) * 4 + reg;
      if (ESED) {
        float esum = 0.f, edsum = 0.f;
#pragma unroll
        for (int nt = 0; nt < 8; ++nt) {
          int col = nt * 16 + (lane & 15);
          esum  = fmaf(acc[mt][nt][reg], sas[col], esum);
          edsum = fmaf(acc[mt][nt][reg], sad[col], edsum);
        }
#pragma unroll
        for (int off = 1; off < 16; off <<= 1) {
          esum  += __shfl_xor(esum, off);
          edsum += __shfl_xor(edsum, off);
        }
        if ((lane & 15) == 0 && row < M) {
          es[row] = esum;
          ed[row] = edsum;
        }
      }
#pragma unroll
      for (int nt = 0; nt < 8; ++nt) {
        float v0 = acc[mt][nt][reg];
        float v1 = __shfl_xor(v0, 1);
        int col = nt * 16 + (lane & 15);
        if (!(lane & 1) && row < M)
          Hb[(size_t)row * 64 + (col >> 1)] = pack2(v0, v1);
      }
    }
  }
}

// ---------------- MLP MFMA GEMM ----------------
template <int RELU, int OUTF32>
__global__ __launch_bounds__(256) void gemm_mlp(const uint32_t* __restrict__ Ab,
                                                const unsigned short* __restrict__ Wp,
                                                const float* __restrict__ bias,
                                                void* __restrict__ outp,
                                                int M, int K, int N) {
  int wave = threadIdx.x >> 6, lane = threadIdx.x & 63;
  int row0 = blockIdx.x * 128 + wave * 32;
  int colb = blockIdx.y;
  const unsigned short* A16 = (const unsigned short*)Ab;
  int KS = K >> 5;
  int r = lane & 15, g = lane >> 4;
  f32x4 acc[2][8];
#pragma unroll
  for (int mt = 0; mt < 2; ++mt)
#pragma unroll
    for (int nt = 0; nt < 8; ++nt) acc[mt][nt] = (f32x4){0.f, 0.f, 0.f, 0.f};

  for (int ks = 0; ks < KS; ++ks) {
    s16x8 a[2];
#pragma unroll
    for (int mt = 0; mt < 2; ++mt) {
      int row = row0 + mt * 16 + r;
      s16x8 af = {0, 0, 0, 0, 0, 0, 0, 0};
      if (row < M) af = *(const s16x8*)(A16 + (size_t)row * K + ks * 32 + g * 8);
      a[mt] = af;
    }
#pragma unroll
    for (int ntl = 0; ntl < 8; ++ntl) {
      int ntg = colb * 8 + ntl;
      s16x8 b = *(const s16x8*)(Wp + ((size_t)(ntg * KS + ks) * 64 + lane) * 8);
      acc[0][ntl] = __builtin_amdgcn_mfma_f32_16x16x32_bf16(a[0], b, acc[0][ntl], 0, 0, 0);
      acc[1][ntl] = __builtin_amdgcn_mfma_f32_16x16x32_bf16(a[1], b, acc[1][ntl], 0, 0, 0);
    }
  }
#pragma unroll
  for (int mt = 0; mt < 2; ++mt) {
#pragma unroll
    for (int ntl = 0; ntl < 8; ++ntl) {
#pragma unroll
      for (int reg = 0; reg < 4; ++reg) {
        int row = row0 + mt * 16 + (lane >> 4) * 4 + reg;
        int col = colb * 128 + ntl * 16 + (lane & 15);
        float v0 = acc[mt][ntl][reg] + bias[col];
        if (RELU) v0 = fmaxf(v0, 0.f);
        if (OUTF32) {
          if (row < M) ((float*)outp)[(size_t)row * N + col] = v0;
        } else {
          float v1 = __shfl_xor(v0, 1);
          if (!(lane & 1) && row < M)
            ((uint32_t*)outp)[(size_t)row * (N >> 1) + (col >> 1)] = pack2(v0, v1);
        }
      }
    }
  }
}

// ---------------- unified aggregation: 2 nodes/wave, padded rows, depth-2 pipeline ----
template <int GAT>
__global__ __launch_bounds__(256) void agg_kernel(const uint2* __restrict__ Hb2,
                                                  const int* __restrict__ rowstart,
                                                  const int2* __restrict__ pack,
                                                  const float* __restrict__ dinv,
                                                  const int* __restrict__ indeg,
                                                  const float* __restrict__ es,
                                                  const float* __restrict__ ed,
                                                  uint32_t* __restrict__ aggb,
                                                  float* __restrict__ stats) {
  const float INVALW = GAT ? -1e30f : 0.0f;
  int tid = threadIdx.x;
  int lane = tid & 63;
  int hl = lane & 31;
  int half = lane >> 5;
  int gw = (blockIdx.x * 256 + tid) >> 6;
  int nw = (gridDim.x * 256) >> 6;
  float s0 = 0, s1 = 0, s2 = 0, s3 = 0, q0 = 0, q1 = 0, q2 = 0, q3 = 0;

#define LOADPK(gq, I0, I1, I2, I3, V0, V1, V2, V3)                        \
  do {                                                                    \
    bool ok = (gq) < G;                                                   \
    int ee = e0 + (gq) * 4;                                               \
    int2 pa = pack[ee], pb = pack[ee + 1], pc = pack[ee + 2], pd = pack[ee + 3]; \
    I0 = ok ? pa.x : 0; V0 = ok ? __int_as_float(pa.y) : INVALW;          \
    I1 = ok ? pb.x : 0; V1 = ok ? __int_as_float(pb.y) : INVALW;          \
    I2 = ok ? pc.x : 0; V2 = ok ? __int_as_float(pc.y) : INVALW;          \
    I3 = ok ? pd.x : 0; V3 = ok ? __int_as_float(pd.y) : INVALW;          \
  } while (0)

  for (int pi = gw; pi < N_NODES / 2; pi += nw) {
    int n = 2 * pi + half;
    int e0 = rowstart[n], e1p = rowstart[n + 1];
    int G = (e1p - e0) >> 2;
    int Gmax = max(G, __shfl_xor(G, 32));
    float edi = 0.f, selfw, fscale = 1.f;
    if (GAT) {
      int len = indeg[n];
      edi = ed[n];
      float wself = __expf(leaky(es[n] + edi));
      float wsum = (hl == 0) ? wself : 0.f;
      for (int e = e0 + hl; e < e0 + len; e += 32)
        wsum += __expf(leaky(__int_as_float(pack[e].y) + edi));
#pragma unroll
      for (int off = 16; off; off >>= 1) wsum += __shfl_xor(wsum, off);
      fscale = 1.f / (wsum + 1e-16f);
      selfw = wself;
    } else {
      float di = dinv[n];
      selfw = di * di;
    }
    uint2 hs = Hb2[(size_t)n * 32 + hl];
    float c0 = blo(hs.x) * selfw, c1 = bhi(hs.x) * selfw;
    float c2 = blo(hs.y) * selfw, c3 = bhi(hs.y) * selfw;

    if (Gmax > 0) {
      int j0, j1, j2, j3;
      float wC0, wC1, wC2, wC3;
      float wB0, wB1, wB2, wB3;
      float wA0, wA1, wA2, wA3;
      uint2 R00, R01, R02, R03;
      uint2 R10, R11, R12, R13;
      LOADPK(0, j0, j1, j2, j3, wC0, wC1, wC2, wC3);
      R00 = Hb2[(size_t)(unsigned)j0 * 32 + hl];
      R01 = Hb2[(size_t)(unsigned)j1 * 32 + hl];
      R02 = Hb2[(size_t)(unsigned)j2 * 32 + hl];
      R03 = Hb2[(size_t)(unsigned)j3 * 32 + hl];
      LOADPK(1, j0, j1, j2, j3, wB0, wB1, wB2, wB3);
      R10 = Hb2[(size_t)(unsigned)j0 * 32 + hl];
      R11 = Hb2[(size_t)(unsigned)j1 * 32 + hl];
      R12 = Hb2[(size_t)(unsigned)j2 * 32 + hl];
      R13 = Hb2[(size_t)(unsigned)j3 * 32 + hl];
      LOADPK(2, j0, j1, j2, j3, wA0, wA1, wA2, wA3);
      for (int g = 0; g < Gmax; ++g) {
        uint2 R20, R21, R22, R23;
        if (g + 2 < Gmax) {
          R20 = Hb2[(size_t)(unsigned)j0 * 32 + hl];
          R21 = Hb2[(size_t)(unsigned)j1 * 32 + hl];
          R22 = Hb2[(size_t)(unsigned)j2 * 32 + hl];
          R23 = Hb2[(size_t)(unsigned)j3 * 32 + hl];
        }
        int k0, k1, k2, k3;
        float wN0, wN1, wN2, wN3;
        if (g + 3 < Gmax) {
          LOADPK(g + 3, k0, k1, k2, k3, wN0, wN1, wN2, wN3);
        } else {
          k0 = k1 = k2 = k3 = 0;
          wN0 = wN1 = wN2 = wN3 = INVALW;
        }
        float f0, f1, f2, f3;
        if (GAT) {
          f0 = __expf(leaky(wC0 + edi)); f1 = __expf(leaky(wC1 + edi));
          f2 = __expf(leaky(wC2 + edi)); f3 = __expf(leaky(wC3 + edi));
        } else {
          f0 = wC0; f1 = wC1; f2 = wC2; f3 = wC3;
        }
        __builtin_amdgcn_s_setprio(1);
        c0 = fmaf(blo(R00.x), f0, c0); c1 = fmaf(bhi(R00.x), f0, c1);
        c2 = fmaf(blo(R00.y), f0, c2); c3 = fmaf(bhi(R00.y), f0, c3);
        c0 = fmaf(blo(R01.x), f1, c0); c1 = fmaf(bhi(R01.x), f1, c1);
        c2 = fmaf(blo(R01.y), f1, c2); c3 = fmaf(bhi(R01.y), f1, c3);
        c0 = fmaf(blo(R02.x), f2, c0); c1 = fmaf(bhi(R02.x), f2, c1);
        c2 = fmaf(blo(R02.y), f2, c2); c3 = fmaf(bhi(R02.y), f2, c3);
        c0 = fmaf(blo(R03.x), f3, c0); c1 = fmaf(bhi(R03.x), f3, c1);
        c2 = fmaf(blo(R03.y), f3, c2); c3 = fmaf(bhi(R03.y), f3, c3);
        __builtin_amdgcn_s_setprio(0);
        R00 = R10; R01 = R11; R02 = R12; R03 = R13;
        R10 = R20; R11 = R21; R12 = R22; R13 = R23;
        wC0 = wB0; wC1 = wB1; wC2 = wB2; wC3 = wB3;
        wB0 = wA0; wB1 = wA1; wB2 = wA2; wB3 = wA3;
        wA0 = wN0; wA1 = wN1; wA2 = wN2; wA3 = wN3;
        j0 = k0; j1 = k1; j2 = k2; j3 = k3;
      }
    }
    if (GAT) { c0 *= fscale; c1 *= fscale; c2 *= fscale; c3 *= fscale; }
    ((uint2*)aggb)[(size_t)n * 32 + hl] = make_uint2(packh2(c0, c1), packh2(c2, c3));
    s0 += c0; s1 += c1; s2 += c2; s3 += c3;
    q0 += c0 * c0; q1 += c1 * c1; q2 += c2 * c2; q3 += c3 * c3;
  }
#undef LOADPK
  s0 += __shfl_xor(s0, 32); s1 += __shfl_xor(s1, 32);
  s2 += __shfl_xor(s2, 32); s3 += __shfl_xor(s3, 32);
  q0 += __shfl_xor(q0, 32); q1 += __shfl_xor(q1, 32);
  q2 += __shfl_xor(q2, 32); q3 += __shfl_xor(q3, 32);
  __shared__ float red[4][128];
  int w = tid >> 6;
  if (half == 0) {
    red[w][4 * hl + 0] = s0; red[w][4 * hl + 1] = s1;
    red[w][4 * hl + 2] = s2; red[w][4 * hl + 3] = s3;
  }
  __syncthreads();
  if (w == 0) {
    float a = red[0][2 * lane] + red[1][2 * lane] + red[2][2 * lane] + red[3][2 * lane];
    float b = red[0][2 * lane + 1] + red[1][2 * lane + 1] + red[2][2 * lane + 1] + red[3][2 * lane + 1];
    atomicAdd(&stats[2 * lane], a);
    atomicAdd(&stats[2 * lane + 1], b);
  }
  __syncthreads();
  if (half == 0) {
    red[w][4 * hl + 0] = q0; red[w][4 * hl + 1] = q1;
    red[w][4 * hl + 2] = q2; red[w][4 * hl + 3] = q3;
  }
  __syncthreads();
  if (w == 0) {
    float a = red[0][2 * lane] + red[1][2 * lane] + red[2][2 * lane] + red[3][2 * lane];
    float b = red[0][2 * lane + 1] + red[1][2 * lane + 1] + red[2][2 * lane + 1] + red[3][2 * lane + 1];
    atomicAdd(&stats[128 + 2 * lane], a);
    atomicAdd(&stats[128 + 2 * lane + 1], b);
  }
}

// overwrite pack.y: pads (y==0) -> -1e30 sentinel; else es[src] (clamped: slots beyond
// rowstart[N] hold garbage that is never consumed, but must not fault on the es read)
__global__ void gat_pack_kernel(int2* __restrict__ sw, const float* __restrict__ es) {
  int e = blockIdx.x * 256 + threadIdx.x;
  if (e < CSR_CAP) {
    int2 v = sw[e];
    int sidx = ((unsigned)v.x < N_NODES) ? v.x : 0;
    v.y = (v.y == 0) ? __float_as_int(-1e30f) : __float_as_int(es[sidx]);
    sw[e] = v;
  }
}

// ---------------- pooling with fused BN+ReLU+residual of last layer; bf16 out ----------------
__global__ __launch_bounds__(256) void pool_bn(const uint32_t* __restrict__ aggb,
                                               const uint32_t* __restrict__ xb,
                                               const float* __restrict__ stats,
                                               const float* __restrict__ gamma,
                                               const float* __restrict__ beta,
                                               const int* __restrict__ gstart,
                                               uint32_t* __restrict__ pooledb) {
  int g = blockIdx.x;
  int c = threadIdx.x & 127;
  int half = threadIdx.x >> 7;
  const float n_inv = 1.f / (float)N_NODES;
  float m = stats[c] * n_inv;
  float v = stats[128 + c] * n_inv - m * m;
  float sc = gamma[c] * rsqrtf(v + BN_EPS);
  float bc = beta[c] - m * sc;
  int s = gstart[g], e = gstart[g + 1];
  float acc = 0.f;
  for (int n = s + half; n < e; n += 2) {
    uint32_t aw = aggb[(size_t)n * 64 + (c >> 1)];
    float a = (c & 1) ? hhi(aw) : hlo(aw);
    uint32_t u = xb[(size_t)n * 64 + (c >> 1)];
    float xo = (c & 1) ? bhi(u) : blo(u);
    acc += fmaxf(fmaf(a, sc, bc), 0.f) + xo;
  }
  __shared__ float red[256];
  __shared__ float fin[128];
  red[threadIdx.x] = acc;
  __syncthreads();
  if (half == 0) {
    float vsum = red[c] + red[128 + c];
    int cnt = e - s;
    fin[c] = vsum / fmaxf((float)cnt, 1.f);
  }
  __syncthreads();
  if (half == 0 && !(c & 1))
    pooledb[(size_t)g * 64 + (c >> 1)] = pack2(fin[c], fin[c + 1]);
}

// ---------------- host launch ----------------
extern "C" void kernel_launch(void* const* d_in, const int* in_sizes, int n_in,
                              void* d_out, int out_size, void* d_ws, size_t ws_size,
                              hipStream_t stream) {
  const float* x_in  = (const float*)d_in[0];
  const int*   eidx  = (const int*)d_in[1];
  const int*   batch = (const int*)d_in[2];
  const float* W1 = (const float*)d_in[3];
  const float* g1 = (const float*)d_in[5];
  const float* be1 = (const float*)d_in[6];
  const float* W2 = (const float*)d_in[7];
  const float* g2 = (const float*)d_in[9];
  const float* be2 = (const float*)d_in[10];
  const float* W3 = (const float*)d_in[11];
  const float* g3 = (const float*)d_in[13];
  const float* be3 = (const float*)d_in[14];
  const float* Wa = (const float*)d_in[15];
  const float* asrc = (const float*)d_in[16];
  const float* adst = (const float*)d_in[17];
  const float* ga = (const float*)d_in[19];
  const float* bea = (const float*)d_in[20];
  const float* Wh1 = (const float*)d_in[21];
  const float* bh1 = (const float*)d_in[22];
  const float* Wm0 = (const float*)d_in[23];
  const float* bm0 = (const float*)d_in[24];
  const float* Wm1 = (const float*)d_in[25];
  const float* bm1 = (const float*)d_in[26];
  const float* Wo = (const float*)d_in[27];
  const float* bo = (const float*)d_in[28];

  const int* src = eidx;
  const int* dst = eidx + N_EDGES;

  char* p = (char*)d_ws;
  auto alloc = [&](size_t bytes) {
    char* r = p;
    p += (bytes + 255) & ~(size_t)255;
    return r;
  };
  // ---- zero-region (one small memset): indeg+cursor, stats ----
  char* zbase = p;
  int*   indeg     = (int*)alloc((size_t)2 * N_NODES * 4);  // indeg + cursor
  int*   cursor    = indeg + N_NODES;
  float* stats     = (float*)alloc(4 * 256 * 4);
  size_t zsize = (size_t)(p - zbase);
  // ---- rest ----
  int2*  csr_sw    = (int2*)alloc((size_t)CSR_CAP * 8);
  uint32_t* Hb     = (uint32_t*)alloc((size_t)N_NODES * 64 * 4);
  uint32_t* xb     = (uint32_t*)alloc((size_t)N_NODES * 64 * 4);
  uint32_t* aggb   = (uint32_t*)alloc((size_t)N_NODES * 64 * 4);   // fp16 pairs
  int*   rowstart  = (int*)alloc((size_t)(N_NODES + 1) * 4);
  float* dinv      = (float*)alloc((size_t)N_NODES * 4);
  float* es        = (float*)alloc((size_t)N_NODES * 4);
  float* ed        = (float*)alloc((size_t)N_NODES * 4);
  int*   chunksum  = (int*)alloc(128 * 4);
  int*   gstart    = (int*)alloc((BG + 1) * 4);
  uint32_t* pooledb = (uint32_t*)alloc((size_t)BG * 64 * 4);
  uint32_t* m1b    = (uint32_t*)alloc((size_t)BG * (NHID / 2) * 4);
  uint32_t* m2b    = (uint32_t*)alloc((size_t)BG * (NHID / 2) * 4);
  unsigned short* Wp1 = (unsigned short*)alloc(2048 * 8 * 2);
  unsigned short* Wp2 = (unsigned short*)alloc(2048 * 8 * 2);
  unsigned short* Wp3 = (unsigned short*)alloc(2048 * 8 * 2);
  unsigned short* Wp4 = (unsigned short*)alloc(2048 * 8 * 2);
  unsigned short* P1 = (unsigned short*)alloc((size_t)8192 * 8 * 2);
  unsigned short* P2 = (unsigned short*)alloc((size_t)32768 * 8 * 2);
  unsigned short* P3 = (unsigned short*)alloc((size_t)32768 * 8 * 2);
  unsigned short* P4 = (unsigned short*)alloc((size_t)16384 * 8 * 2);

  hipMemsetAsync(zbase, 0, zsize, stream);

  // CSR build (padded rows; pads zeroed in scan_finish)
  hist_kernel<<<(N_EDGES + 255) / 256, 256, 0, stream>>>(dst, indeg);
  scan_chunks<<<98, 256, 0, stream>>>(indeg, rowstart, chunksum);
  scan_finish<<<(N_NODES + 256) / 256, 256, 0, stream>>>(chunksum, rowstart, indeg, dinv, csr_sw);
  scatter_edges<<<(N_EDGES + 255) / 256, 256, 0, stream>>>(src, dst, rowstart, cursor, dinv, csr_sw);

  // prep: cast x + pack conv/MLP weights + graph_starts (single dispatch)
  prep_kernel<<<25384 + 391, 256, 0, stream>>>((const float2*)x_in, xb, W1, W2, W3, Wa,
                                               Wp1, Wp2, Wp3, Wp4,
                                               Wh1, Wm0, Wm1, Wo, P1, P2, P3, P4,
                                               batch, gstart);

  const int gemm_blocks_m = (N_NODES + 127) / 128;  // 782
  const int AGG_BLOCKS = 2048;

  // layer 1
  gemm_mfma<0, 0><<<gemm_blocks_m, 256, 0, stream>>>(xb, nullptr, nullptr, nullptr, nullptr,
                                                     Wp1, Hb, nullptr, nullptr, nullptr, nullptr, N_NODES);
  agg_kernel<0><<<AGG_BLOCKS, 256, 0, stream>>>((const uint2*)Hb, rowstart, csr_sw,
                                                dinv, indeg, nullptr, nullptr, aggb, stats + 0 * 256);
  // layer 2 (fuse BN1)
  gemm_mfma<1, 0><<<gemm_blocks_m, 256, 0, stream>>>(xb, aggb, stats + 0 * 256, g1, be1,
                                                     Wp2, Hb, nullptr, nullptr, nullptr, nullptr, N_NODES);
  agg_kernel<0><<<AGG_BLOCKS, 256, 0, stream>>>((const uint2*)Hb, rowstart, csr_sw,
                                                dinv, indeg, nullptr, nullptr, aggb, stats + 1 * 256);
  // layer 3 (fuse BN2)
  gemm_mfma<1, 0><<<gemm_blocks_m, 256, 0, stream>>>(xb, aggb, stats + 1 * 256, g2, be2,
                                                     Wp3, Hb, nullptr, nullptr, nullptr, nullptr, N_NODES);
  agg_kernel<0><<<AGG_BLOCKS, 256, 0, stream>>>((const uint2*)Hb, rowstart, csr_sw,
                                                dinv, indeg, nullptr, nullptr, aggb, stats + 2 * 256);
  // layer 4 = GAT (fuse BN3 + es/ed)
  gemm_mfma<1, 1><<<gemm_blocks_m, 256, 0, stream>>>(xb, aggb, stats + 2 * 256, g3, be3,
                                                     Wp4, Hb, asrc, adst, es, ed, N_NODES);
  gat_pack_kernel<<<(CSR_CAP + 255) / 256, 256, 0, stream>>>(csr_sw, es);
  agg_kernel<1><<<AGG_BLOCKS, 256, 0, stream>>>((const uint2*)Hb, rowstart, csr_sw,
                                                nullptr, indeg, es, ed, aggb, stats + 3 * 256);

  // pooling (fuses BN4), bf16 out
  pool_bn<<<BG, 256, 0, stream>>>(aggb, xb, stats + 3 * 256, ga, bea, gstart, pooledb);

  // MLP head (MFMA bf16)
  gemm_mlp<1, 0><<<dim3(4, 4), 256, 0, stream>>>(pooledb, P1, bh1, m1b, BG, CCH, NHID);
  gemm_mlp<1, 0><<<dim3(4, 4), 256, 0, stream>>>(m1b, P2, bm0, m2b, BG, NHID, NHID);
  gemm_mlp<1, 0><<<dim3(4, 4), 256, 0, stream>>>(m2b, P3, bm1, m1b, BG, NHID, NHID);
  gemm_mlp<0, 1><<<dim3(4, 2), 256, 0, stream>>>(m1b, P4, bo, d_out, BG, NHID, NOUT);
}